// Round 1
// baseline (2246.960 us; speedup 1.0000x reference)
//
#include <hip/hip_runtime.h>
#include <math.h>

// GraphMatcher: L=18 layers, D=256, B=2 (-> 4 batch rows), N=1024, H=4, HD=64.
// State d = [4][256][1024] f32 in ws. Per layer:
//   castx: y[:,0:256,:] = bf16(d)
//   proj : q/k/v = Wq/Wk/Wv @ x(+perm for cross) + b     (bf16 MFMA GEMM)
//   attn : fused flash attention per (b,h), out att bf16
//   merge: y[:,256:512,:] = Wm @ att + bm
//   mlp1 : h = relu(BN(W1 @ y + b1))   (BN folded to sc*acc+sh)
//   mlp2 : d += W2 @ h + b2 ; cross layers also write d_out
// All GEMM inputs bf16 (weights pre-cast once per call), accum f32.

typedef unsigned short u16;
typedef unsigned int u32;
typedef __attribute__((ext_vector_type(4))) unsigned int u32x4;
typedef __attribute__((ext_vector_type(2))) unsigned int u32x2;
typedef __attribute__((ext_vector_type(8))) short short8v;
typedef __attribute__((ext_vector_type(4))) float f32x4;

union AB {
  u32x4 q;
  u32x2 d[2];
  short8v s;
};

__device__ __forceinline__ u16 f2bf(float f) {  // f32 -> bf16 RNE
  u32 u = __builtin_bit_cast(u32, f);
  u32 r = u + 0x7fffu + ((u >> 16) & 1u);
  return (u16)(r >> 16);
}

// ---------------- generic 128x128 bf16 GEMM core (K = 256 or 512) ----------
// Wt: bf16 weight tile base (W + bm*K), rows [128][K], k-contiguous.
// X : bf16 activations [K][1024], rows n-contiguous. bn = n-tile offset.
// LDS: X-tile transposed [128 n][32 k] at 72B row stride (b64-readable).
template<int K>
__device__ __forceinline__ void gemm_core(const u16* __restrict__ Wt,
                                          const u16* __restrict__ X,
                                          int bn, char* lds, f32x4 (&acc)[4][4]) {
  const int tid = threadIdx.x;
  const int lane = tid & 63, l4 = lane >> 4, l15 = lane & 15;
  const int w = tid >> 6, wm = w >> 1, wn = w & 1;
  const int kk = tid & 31, nn0 = (tid >> 5) * 16;

#pragma unroll
  for (int a = 0; a < 4; ++a)
#pragma unroll
    for (int b = 0; b < 4; ++b) acc[a][b] = (f32x4){0.f, 0.f, 0.f, 0.f};

  for (int k0 = 0; k0 < K; k0 += 32) {
    // gather-read 16 consecutive n at row (k0+kk)  (overlaps prev MFMA)
    const u16* src = X + (k0 + kk) * 1024 + bn + nn0;
    u32x4 va = *(const u32x4*)src;
    u32x4 vb = *(const u32x4*)(src + 8);
    __syncthreads();  // prior iteration's LDS reads done
    {
      char* wr = lds + kk * 2;
#pragma unroll
      for (int e = 0; e < 8; ++e)
        *(u16*)(wr + (nn0 + e) * 72) = (u16)(va[e >> 1] >> ((e & 1) * 16));
#pragma unroll
      for (int e = 0; e < 8; ++e)
        *(u16*)(wr + (nn0 + 8 + e) * 72) = (u16)(vb[e >> 1] >> ((e & 1) * 16));
    }
    __syncthreads();
    AB bf[4];
#pragma unroll
    for (int sn = 0; sn < 4; ++sn) {  // B frag: col = local n = l15, k 8-contig
      const char* ra = lds + (wn * 64 + sn * 16 + l15) * 72 + l4 * 16;
      bf[sn].d[0] = *(const u32x2*)ra;
      bf[sn].d[1] = *(const u32x2*)(ra + 8);
    }
#pragma unroll
    for (int sm = 0; sm < 4; ++sm) {  // A frag: row = out ch = l15, k 8-contig
      AB af;
      af.q = *(const u32x4*)(Wt + (wm * 64 + sm * 16 + l15) * K + k0 + l4 * 8);
#pragma unroll
      for (int sn = 0; sn < 4; ++sn)
        acc[sm][sn] =
            __builtin_amdgcn_mfma_f32_16x16x32_bf16(af.s, bf[sn].s, acc[sm][sn], 0, 0, 0);
    }
  }
}

// ---------------- small kernels ----------------
__global__ void k_wcast(const float* __restrict__ src, u16* __restrict__ dst,
                        int shift, int stride) {
  size_t i4 = ((size_t)blockIdx.x * 256 + threadIdx.x) * 4;  // grid sized exactly
  int layer = (int)(i4 >> shift);
  size_t rem = i4 & (((size_t)1 << shift) - 1);
  f32x4 a = *(const f32x4*)(src + i4);
  u32x2 pk;
  pk[0] = (u32)f2bf(a[0]) | ((u32)f2bf(a[1]) << 16);
  pk[1] = (u32)f2bf(a[2]) | ((u32)f2bf(a[3]) << 16);
  *(u32x2*)(dst + (size_t)layer * stride + rem) = pk;
}

__global__ void k_bnprep(const float* __restrict__ g, const float* __restrict__ be,
                         const float* __restrict__ mu, const float* __restrict__ va,
                         const float* __restrict__ b1, float* __restrict__ sc,
                         float* __restrict__ sh) {
  int i = blockIdx.x * 256 + threadIdx.x;
  if (i >= 18 * 512) return;
  float s = g[i] * rsqrtf(va[i] + 1e-5f);
  sc[i] = s;
  sh[i] = s * (b1[i] - mu[i]) + be[i];
}

__global__ void k_castx(const float* __restrict__ d, u16* __restrict__ y) {
  size_t i8 = ((size_t)blockIdx.x * 256 + threadIdx.x) * 8;  // 512 blocks exact
  int b = (int)(i8 >> 18);
  size_t rem = i8 & 262143;
  const float* s = d + ((size_t)b << 18) + rem;
  f32x4 a = *(const f32x4*)s;
  f32x4 c = *(const f32x4*)(s + 4);
  u32x4 pk;
  pk[0] = (u32)f2bf(a[0]) | ((u32)f2bf(a[1]) << 16);
  pk[1] = (u32)f2bf(a[2]) | ((u32)f2bf(a[3]) << 16);
  pk[2] = (u32)f2bf(c[0]) | ((u32)f2bf(c[1]) << 16);
  pk[3] = (u32)f2bf(c[2]) | ((u32)f2bf(c[3]) << 16);
  *(u32x4*)(y + (size_t)b * 524288 + rem) = pk;
}

// ---------------- GEMM wrapper kernels ----------------
__global__ __launch_bounds__(256) void k_proj(
    const u16* __restrict__ wl, const u16* __restrict__ y, const float* __restrict__ bq,
    const float* __restrict__ bk, const float* __restrict__ bv, u16* __restrict__ q,
    u16* __restrict__ k, u16* __restrict__ v, int crossmask) {
  __shared__ alignas(16) char lds[128 * 72];
  int z = blockIdx.z, p = z >> 2, b = z & 3;
  int bm = blockIdx.y * 128, bn = blockIdx.x * 128;
  const u16* W = wl + p * 65536 + bm * 256;
  int srcb = p ? (b ^ crossmask) : b;  // cross: k,v read src = batches [2,3,0,1]
  const u16* X = y + (size_t)srcb * 524288;  // y channels 0..255 = x
  const float* bias = (p == 0) ? bq : ((p == 1) ? bk : bv);
  u16* outb = ((p == 0) ? q : ((p == 1) ? k : v)) + (size_t)b * 262144;
  f32x4 acc[4][4];
  gemm_core<256>(W, X, bn, lds, acc);
  int lane = threadIdx.x & 63, l4 = lane >> 4, l15 = lane & 15;
  int w = threadIdx.x >> 6, wm = w >> 1, wn = w & 1;
#pragma unroll
  for (int sm = 0; sm < 4; ++sm)
#pragma unroll
    for (int r = 0; r < 4; ++r) {
      int row = bm + wm * 64 + sm * 16 + l4 * 4 + r;
      float bb = bias[row];
#pragma unroll
      for (int sn = 0; sn < 4; ++sn) {
        int col = bn + wn * 64 + sn * 16 + l15;
        outb[(size_t)row * 1024 + col] = f2bf(acc[sm][sn][r] + bb);
      }
    }
}

__global__ __launch_bounds__(256) void k_merge(const u16* __restrict__ Wm,
                                               const u16* __restrict__ attb,
                                               const float* __restrict__ bias,
                                               u16* __restrict__ y) {
  __shared__ alignas(16) char lds[128 * 72];
  int b = blockIdx.z;
  int bm = blockIdx.y * 128, bn = blockIdx.x * 128;
  f32x4 acc[4][4];
  gemm_core<256>(Wm + bm * 256, attb + (size_t)b * 262144, bn, lds, acc);
  u16* outb = y + (size_t)b * 524288 + 262144;  // y channels 256..511
  int lane = threadIdx.x & 63, l4 = lane >> 4, l15 = lane & 15;
  int w = threadIdx.x >> 6, wm = w >> 1, wn = w & 1;
#pragma unroll
  for (int sm = 0; sm < 4; ++sm)
#pragma unroll
    for (int r = 0; r < 4; ++r) {
      int row = bm + wm * 64 + sm * 16 + l4 * 4 + r;
      float bb = bias[row];
#pragma unroll
      for (int sn = 0; sn < 4; ++sn) {
        int col = bn + wn * 64 + sn * 16 + l15;
        outb[(size_t)row * 1024 + col] = f2bf(acc[sm][sn][r] + bb);
      }
    }
}

__global__ __launch_bounds__(256) void k_mlp1(const u16* __restrict__ W1,
                                              const u16* __restrict__ y,
                                              const float* __restrict__ sc,
                                              const float* __restrict__ sh,
                                              u16* __restrict__ hb) {
  __shared__ alignas(16) char lds[128 * 72];
  int b = blockIdx.z;
  int bm = blockIdx.y * 128, bn = blockIdx.x * 128;
  f32x4 acc[4][4];
  gemm_core<512>(W1 + bm * 512, y + (size_t)b * 524288, bn, lds, acc);
  u16* outb = hb + (size_t)b * 524288;
  int lane = threadIdx.x & 63, l4 = lane >> 4, l15 = lane & 15;
  int w = threadIdx.x >> 6, wm = w >> 1, wn = w & 1;
#pragma unroll
  for (int sm = 0; sm < 4; ++sm)
#pragma unroll
    for (int r = 0; r < 4; ++r) {
      int row = bm + wm * 64 + sm * 16 + l4 * 4 + r;
      float s_ = sc[row], t_ = sh[row];
#pragma unroll
      for (int sn = 0; sn < 4; ++sn) {
        int col = bn + wn * 64 + sn * 16 + l15;
        float val = fmaxf(s_ * acc[sm][sn][r] + t_, 0.f);
        outb[(size_t)row * 1024 + col] = f2bf(val);
      }
    }
}

__global__ __launch_bounds__(256) void k_mlp2(const u16* __restrict__ W2,
                                              const u16* __restrict__ hb,
                                              const float* __restrict__ b2,
                                              float* __restrict__ dstate,
                                              float* __restrict__ out, int cross, int j) {
  __shared__ alignas(16) char lds[128 * 72];
  int b = blockIdx.z;
  int bm = blockIdx.y * 128, bn = blockIdx.x * 128;
  f32x4 acc[4][4];
  gemm_core<512>(W2 + bm * 512, hb + (size_t)b * 524288, bn, lds, acc);
  int lane = threadIdx.x & 63, l4 = lane >> 4, l15 = lane & 15;
  int w = threadIdx.x >> 6, wm = w >> 1, wn = w & 1;
#pragma unroll
  for (int sm = 0; sm < 4; ++sm)
#pragma unroll
    for (int r = 0; r < 4; ++r) {
      int row = bm + wm * 64 + sm * 16 + l4 * 4 + r;
      float bb = b2[row];
#pragma unroll
      for (int sn = 0; sn < 4; ++sn) {
        int col = bn + wn * 64 + sn * 16 + l15;
        size_t di = ((size_t)b << 18) + (size_t)row * 1024 + col;
        float nv = dstate[di] + acc[sm][sn][r] + bb;
        dstate[di] = nv;
        if (cross)
          out[(((size_t)((b >> 1) * 9 + j) * 2 + (b & 1)) << 18) + (size_t)row * 1024 + col] = nv;
      }
    }
}

// ---------------- fused flash attention ----------------
// grid (16 n-blocks of 64, 16 b*h). 4 waves, each wave 16 q-rows, full m sweep
// in 64-chunks with online softmax. Q,K transposed into LDS [n][hd] / [m][hd]
// (136B row stride); P round-trips LDS per wave for the PV A-fragment.
__global__ __launch_bounds__(256) void k_attn(const u16* __restrict__ q,
                                              const u16* __restrict__ k,
                                              const u16* __restrict__ v,
                                              u16* __restrict__ att) {
  __shared__ alignas(16) char Qs[64 * 136];
  __shared__ alignas(16) char Ks[64 * 136];
  __shared__ alignas(16) char Ps[4][16 * 136];
  const int nb = blockIdx.x * 64;
  const int bh = blockIdx.y, b = bh >> 2, hh = bh & 3;
  const int tid = threadIdx.x, w = tid >> 6, lane = tid & 63;
  const int l4 = lane >> 4, l15 = lane & 15;
  const u16* qp = q + (size_t)b * 262144 + hh * 1024;  // channel hd*4+hh -> +hd*4096
  const u16* kp = k + (size_t)b * 262144 + hh * 1024;
  const u16* vp = v + (size_t)b * 262144 + hh * 1024;

  {  // stage Q transposed: Qs[n_local][hd]
    int hd = tid & 63, n0 = (tid >> 6) * 16;
    const u16* s = qp + (size_t)hd * 4096 + nb + n0;
    u32x4 a = *(const u32x4*)s, c = *(const u32x4*)(s + 8);
    char* wr = Qs + hd * 2;
#pragma unroll
    for (int e = 0; e < 8; ++e)
      *(u16*)(wr + (n0 + e) * 136) = (u16)(a[e >> 1] >> ((e & 1) * 16));
#pragma unroll
    for (int e = 0; e < 8; ++e)
      *(u16*)(wr + (n0 + 8 + e) * 136) = (u16)(c[e >> 1] >> ((e & 1) * 16));
  }
  __syncthreads();
  AB qf[2];  // Q A-frags hoisted (row = w*16+l15, k=hd)
#pragma unroll
  for (int ks = 0; ks < 2; ++ks) {
    const char* ra = Qs + (w * 16 + l15) * 136 + ks * 64 + l4 * 16;
    qf[ks].d[0] = *(const u32x2*)ra;
    qf[ks].d[1] = *(const u32x2*)(ra + 8);
  }

  f32x4 oacc[4];
#pragma unroll
  for (int sh = 0; sh < 4; ++sh) oacc[sh] = (f32x4){0.f, 0.f, 0.f, 0.f};
  float mst[4] = {-1e30f, -1e30f, -1e30f, -1e30f};
  float lst[4] = {0.f, 0.f, 0.f, 0.f};

  for (int m0 = 0; m0 < 1024; m0 += 64) {
    // stage K tile transposed: Ks[m_local][hd]
    int hd = tid & 63, mm0 = (tid >> 6) * 16;
    const u16* s = kp + (size_t)hd * 4096 + m0 + mm0;
    u32x4 a = *(const u32x4*)s, c = *(const u32x4*)(s + 8);
    __syncthreads();  // previous iteration's Ks reads done
    {
      char* wr = Ks + hd * 2;
#pragma unroll
      for (int e = 0; e < 8; ++e)
        *(u16*)(wr + (mm0 + e) * 136) = (u16)(a[e >> 1] >> ((e & 1) * 16));
#pragma unroll
      for (int e = 0; e < 8; ++e)
        *(u16*)(wr + (mm0 + 8 + e) * 136) = (u16)(c[e >> 1] >> ((e & 1) * 16));
    }
    __syncthreads();
    // S = (Q^T)(K^T)^T  -> rows n, cols m
    f32x4 sa[4];
#pragma unroll
    for (int sm = 0; sm < 4; ++sm) {
      sa[sm] = (f32x4){0.f, 0.f, 0.f, 0.f};
#pragma unroll
      for (int ks = 0; ks < 2; ++ks) {
        AB kf;
        const char* ra = Ks + (sm * 16 + l15) * 136 + ks * 64 + l4 * 16;
        kf.d[0] = *(const u32x2*)ra;
        kf.d[1] = *(const u32x2*)(ra + 8);
        sa[sm] = __builtin_amdgcn_mfma_f32_16x16x32_bf16(qf[ks].s, kf.s, sa[sm], 0, 0, 0);
      }
    }
#pragma unroll
    for (int sm = 0; sm < 4; ++sm)
#pragma unroll
      for (int r = 0; r < 4; ++r) sa[sm][r] *= 0.125f;  // 1/sqrt(64)

    // online softmax; lane's rows: w*16 + 4*l4 + r
    float corr[4];
#pragma unroll
    for (int r = 0; r < 4; ++r) {
      float m1 = fmaxf(fmaxf(sa[0][r], sa[1][r]), fmaxf(sa[2][r], sa[3][r]));
#pragma unroll
      for (int dd = 1; dd < 16; dd <<= 1) m1 = fmaxf(m1, __shfl_xor(m1, dd));
      float mnew = fmaxf(mst[r], m1);
      corr[r] = __expf(mst[r] - mnew);
      mst[r] = mnew;
      float rs = 0.f;
#pragma unroll
      for (int sm = 0; sm < 4; ++sm) {
        float pv = __expf(sa[sm][r] - mnew);
        sa[sm][r] = pv;
        rs += pv;
      }
#pragma unroll
      for (int dd = 1; dd < 16; dd <<= 1) rs += __shfl_xor(rs, dd);
      lst[r] = lst[r] * corr[r] + rs;
    }
#pragma unroll
    for (int sh = 0; sh < 4; ++sh)
#pragma unroll
      for (int r = 0; r < 4; ++r) oacc[sh][r] *= corr[r];
    // P -> bf16 -> LDS (wave-private region), rows n, cols m
#pragma unroll
    for (int sm = 0; sm < 4; ++sm)
#pragma unroll
      for (int r = 0; r < 4; ++r)
        *(u16*)(Ps[w] + (l4 * 4 + r) * 136 + (sm * 16 + l15) * 2) = f2bf(sa[sm][r]);
    // PV: A = P (row n = l15, k = m), B = V^T (col hd = l15, k = m, direct global)
#pragma unroll
    for (int ks = 0; ks < 2; ++ks) {
      AB pf;
      const char* ra = Ps[w] + l15 * 136 + ks * 64 + l4 * 16;
      pf.d[0] = *(const u32x2*)ra;
      pf.d[1] = *(const u32x2*)(ra + 8);
#pragma unroll
      for (int sh = 0; sh < 4; ++sh) {
        AB vf;
        vf.q = *(const u32x4*)(vp + (size_t)(sh * 16 + l15) * 4096 + m0 + ks * 32 + l4 * 8);
        oacc[sh] = __builtin_amdgcn_mfma_f32_16x16x32_bf16(pf.s, vf.s, oacc[sh], 0, 0, 0);
      }
    }
  }
  // finalize: att = oacc / l ; transpose via wave-private LDS, store coalesced
  float inv[4];
#pragma unroll
  for (int r = 0; r < 4; ++r) inv[r] = 1.f / lst[r];
#pragma unroll
  for (int sh = 0; sh < 4; ++sh)
#pragma unroll
    for (int r = 0; r < 4; ++r)
      *(u16*)(Ps[w] + (l4 * 4 + r) * 136 + (sh * 16 + l15) * 2) = f2bf(oacc[sh][r] * inv[r]);
  u16 tb[16];
#pragma unroll
  for (int nn = 0; nn < 16; ++nn) tb[nn] = *(const u16*)(Ps[w] + nn * 136 + lane * 2);
  u32x4 o0, o1;
#pragma unroll
  for (int e = 0; e < 4; ++e) o0[e] = (u32)tb[2 * e] | ((u32)tb[2 * e + 1] << 16);
#pragma unroll
  for (int e = 0; e < 4; ++e) o1[e] = (u32)tb[8 + 2 * e] | ((u32)tb[8 + 2 * e + 1] << 16);
  u16* dst = att + (size_t)b * 262144 + (size_t)(lane * 4 + hh) * 1024 + nb + w * 16;
  *(u32x4*)dst = o0;
  *(u32x4*)(dst + 8) = o1;
}

// ---------------- host ----------------
extern "C" void kernel_launch(void* const* d_in, const int* in_sizes, int n_in,
                              void* d_out, int out_size, void* d_ws, size_t ws_size,
                              hipStream_t stream) {
  const float* desc0 = (const float*)d_in[0];
  const float* desc1 = (const float*)d_in[1];
  const float* Wq = (const float*)d_in[2];
  const float* bq = (const float*)d_in[3];
  const float* Wk = (const float*)d_in[4];
  const float* bk = (const float*)d_in[5];
  const float* Wv = (const float*)d_in[6];
  const float* bv = (const float*)d_in[7];
  const float* Wm = (const float*)d_in[8];
  const float* bm = (const float*)d_in[9];
  const float* W1 = (const float*)d_in[10];
  const float* b1 = (const float*)d_in[11];
  const float* gamma = (const float*)d_in[12];
  const float* beta = (const float*)d_in[13];
  const float* mu = (const float*)d_in[14];
  const float* var = (const float*)d_in[15];
  const float* W2 = (const float*)d_in[16];
  const float* b2 = (const float*)d_in[17];

  char* ws = (char*)d_ws;  // ~46 MB used
  float* dstate = (float*)ws;                       // [4][256][1024] f32, 4MB
  u16* y = (u16*)(ws + ((size_t)4 << 20));          // [4][512][1024] bf16 (x | msg)
  u16* qb = (u16*)(ws + ((size_t)8 << 20));
  u16* kb = (u16*)(ws + ((size_t)10 << 20));
  u16* vb = (u16*)(ws + ((size_t)12 << 20));
  u16* attb = (u16*)(ws + ((size_t)14 << 20));
  u16* hb = (u16*)(ws + ((size_t)16 << 20));        // [4][512][1024] bf16
  u16* wbf = (u16*)(ws + ((size_t)20 << 20));       // 18 * 655360 bf16 = 22.5MB
  float* scb = (float*)(ws + ((size_t)44 << 20));   // 18*512 f32
  float* shb = (float*)(ws + ((size_t)45 << 20));

  hipMemcpyAsync(dstate, desc0, (size_t)524288 * 4, hipMemcpyDeviceToDevice, stream);
  hipMemcpyAsync(dstate + 524288, desc1, (size_t)524288 * 4, hipMemcpyDeviceToDevice, stream);

  // weights -> bf16, per-layer packed [Wq Wk Wv Wm W1 W2] stride 655360
  k_wcast<<<1152, 256, 0, stream>>>(Wq, wbf + 0, 16, 655360);
  k_wcast<<<1152, 256, 0, stream>>>(Wk, wbf + 65536, 16, 655360);
  k_wcast<<<1152, 256, 0, stream>>>(Wv, wbf + 131072, 16, 655360);
  k_wcast<<<1152, 256, 0, stream>>>(Wm, wbf + 196608, 16, 655360);
  k_wcast<<<4608, 256, 0, stream>>>(W1, wbf + 262144, 18, 655360);
  k_wcast<<<2304, 256, 0, stream>>>(W2, wbf + 524288, 17, 655360);
  k_bnprep<<<36, 256, 0, stream>>>(gamma, beta, mu, var, b1, scb, shb);

  for (int i = 0; i < 18; ++i) {
    int cross = i & 1;
    const u16* wl = wbf + (size_t)i * 655360;
    k_castx<<<512, 256, 0, stream>>>(dstate, y);
    k_proj<<<dim3(8, 2, 12), 256, 0, stream>>>(wl, y, bq + i * 256, bk + i * 256,
                                               bv + i * 256, qb, kb, vb, cross ? 2 : 0);
    k_attn<<<dim3(16, 16), 256, 0, stream>>>(qb, kb, vb, attb);
    k_merge<<<dim3(8, 2, 4), 256, 0, stream>>>(wl + 196608, attb, bm + i * 256, y);
    k_mlp1<<<dim3(8, 4, 4), 256, 0, stream>>>(wl + 262144, y, scb + (size_t)i * 512,
                                              shb + (size_t)i * 512, hb);
    k_mlp2<<<dim3(8, 2, 4), 256, 0, stream>>>(wl + 524288, hb, b2 + i * 256, dstate,
                                              (float*)d_out, cross, i >> 1);
  }
}

// Round 2
// 2116.203 us; speedup vs baseline: 1.0618x; 1.0618x over previous
//
#include <hip/hip_runtime.h>
#include <math.h>

// GraphMatcher, layout-flipped build: all activations n-major [b][n][c].
//   dstate [4][1024][256] f32 ; y [4][1024][512] bf16 (x | msg)
//   kbuf [4][1024][256] bf16 (c' = h*64+hd) ; vbuf [4][256][1024] bf16 (rows c')
//   attb [4][1024][256] bf16 ; hb [4][1024][512] bf16
// GEMMs read both operands straight from global (16B frags), no LDS, no barriers.
// Wq/Wk/Wv rows permuted hd*4+h -> h*64+hd at cast; Wm cols inverse-permuted;
// 1/sqrt(64) folded into Wq'/bq. Q-proj fused into attn; castx fused into mlp2.

typedef unsigned short u16;
typedef unsigned int u32;
typedef __attribute__((ext_vector_type(4))) unsigned int u32x4;
typedef __attribute__((ext_vector_type(2))) unsigned int u32x2;
typedef __attribute__((ext_vector_type(8))) short short8v;
typedef __attribute__((ext_vector_type(4))) float f32x4;

union AB { u32x4 q; u32x2 d[2]; short8v s; };

__device__ __forceinline__ u16 f2bf(float f) {  // f32 -> bf16 RNE
  u32 u = __builtin_bit_cast(u32, f);
  u32 r = u + 0x7fffu + ((u >> 16) & 1u);
  return (u16)(r >> 16);
}

// 128x128 tile GEMM, no LDS: A rows (M) l15-indexed, B rows (N) l15-indexed,
// both k-contiguous. Caller pre-offsets A,B to the wave's 64x64 quadrant.
template<int LDA, int LDB, int K>
__device__ __forceinline__ void gemm_nl(const u16* __restrict__ A, const u16* __restrict__ B,
                                        f32x4 (&acc)[4][4], int l4, int l15) {
#pragma unroll
  for (int a = 0; a < 4; ++a)
#pragma unroll
    for (int c = 0; c < 4; ++c) acc[a][c] = (f32x4){0.f, 0.f, 0.f, 0.f};
  const u16* Ap = A + l15 * LDA + l4 * 8;
  const u16* Bp = B + l15 * LDB + l4 * 8;
#pragma unroll 2
  for (int k0 = 0; k0 < K; k0 += 32) {
    AB af[4], bf[4];
#pragma unroll
    for (int sm = 0; sm < 4; ++sm) af[sm].q = *(const u32x4*)(Ap + sm * 16 * LDA + k0);
#pragma unroll
    for (int sn = 0; sn < 4; ++sn) bf[sn].q = *(const u32x4*)(Bp + sn * 16 * LDB + k0);
#pragma unroll
    for (int sm = 0; sm < 4; ++sm)
#pragma unroll
      for (int sn = 0; sn < 4; ++sn)
        acc[sm][sn] =
            __builtin_amdgcn_mfma_f32_16x16x32_bf16(af[sm].s, bf[sn].s, acc[sm][sn], 0, 0, 0);
  }
}

// ---------------- setup: weight cast/permute + BN prep, one launch ----------
__global__ void k_setup(const float* __restrict__ Wq, const float* __restrict__ Wk,
                        const float* __restrict__ Wv, const float* __restrict__ Wm,
                        const float* __restrict__ W1, const float* __restrict__ W2,
                        const float* __restrict__ g, const float* __restrict__ be,
                        const float* __restrict__ mu, const float* __restrict__ va,
                        const float* __restrict__ b1, u16* __restrict__ wbf,
                        float* __restrict__ sc, float* __restrict__ sh) {
  int bid = blockIdx.x, tid = threadIdx.x;
  if (bid < 4608) {  // Wq/Wk/Wv (row-permute) and Wm (col-permute)
    int which = bid / 1152, lb = bid - which * 1152;
    size_t i4 = ((size_t)lb * 256 + tid) * 4;
    int layer = (int)(i4 >> 16), rem = (int)(i4 & 65535);
    int row = rem >> 8, kk = rem & 255;
    const float* src = which == 0 ? Wq : which == 1 ? Wk : which == 2 ? Wv : Wm;
    f32x4 a = *(const f32x4*)(src + i4);
    u16* dl = wbf + (size_t)layer * 655360 + which * 65536;
    if (which < 3) {
      float s = (which == 0) ? 0.125f : 1.0f;
      int rp = ((row & 3) << 6) | (row >> 2);
      u32x2 pk;
      pk[0] = (u32)f2bf(a[0] * s) | ((u32)f2bf(a[1] * s) << 16);
      pk[1] = (u32)f2bf(a[2] * s) | ((u32)f2bf(a[3] * s) << 16);
      *(u32x2*)(dl + rp * 256 + kk) = pk;
    } else {
#pragma unroll
      for (int e = 0; e < 4; ++e) {
        int ci = kk + e, cp = ((ci & 3) << 6) | (ci >> 2);
        dl[row * 256 + cp] = f2bf(a[e]);
      }
    }
  } else if (bid < 9216) {  // W1 plain
    int lb = bid - 4608;
    size_t i4 = ((size_t)lb * 256 + tid) * 4;
    int layer = (int)(i4 >> 18);
    size_t rem = i4 & 262143;
    f32x4 a = *(const f32x4*)(W1 + i4);
    u32x2 pk;
    pk[0] = (u32)f2bf(a[0]) | ((u32)f2bf(a[1]) << 16);
    pk[1] = (u32)f2bf(a[2]) | ((u32)f2bf(a[3]) << 16);
    *(u32x2*)(wbf + (size_t)layer * 655360 + 262144 + rem) = pk;
  } else if (bid < 11520) {  // W2 plain
    int lb = bid - 9216;
    size_t i4 = ((size_t)lb * 256 + tid) * 4;
    int layer = (int)(i4 >> 17);
    size_t rem = i4 & 131071;
    f32x4 a = *(const f32x4*)(W2 + i4);
    u32x2 pk;
    pk[0] = (u32)f2bf(a[0]) | ((u32)f2bf(a[1]) << 16);
    pk[1] = (u32)f2bf(a[2]) | ((u32)f2bf(a[3]) << 16);
    *(u32x2*)(wbf + (size_t)layer * 655360 + 524288 + rem) = pk;
  } else {  // BN prep: sc = g*rsqrt(var+eps), sh = sc*(b1-mu)+beta
    int i = (bid - 11520) * 256 + tid;
    if (i < 9216) {
      float s = g[i] * rsqrtf(va[i] + 1e-5f);
      sc[i] = s;
      sh[i] = s * (b1[i] - mu[i]) + be[i];
    }
  }
}

// ---------------- init: desc [c][n] f32 -> dstate [n][c] f32 + y bf16 -------
__global__ __launch_bounds__(256) void k_init(const float* __restrict__ d0,
                                              const float* __restrict__ d1,
                                              float* __restrict__ dstate,
                                              u16* __restrict__ y) {
  __shared__ float T[64 * 65];
  int b = blockIdx.z, cb = blockIdx.y * 64, nb = blockIdx.x * 64;
  int t = threadIdx.x, th = t >> 4, tl = t & 15;
  const float* src = (b < 2 ? d0 : d1) + (size_t)(b & 1) * 262144;
#pragma unroll
  for (int it = 0; it < 4; ++it) {
    int cl = it * 16 + th;
    f32x4 v = *(const f32x4*)(src + (size_t)(cb + cl) * 1024 + nb + tl * 4);
#pragma unroll
    for (int e = 0; e < 4; ++e) T[cl * 65 + tl * 4 + e] = v[e];
  }
  __syncthreads();
#pragma unroll
  for (int it = 0; it < 4; ++it) {
    int nl = it * 16 + th;
    f32x4 o;
#pragma unroll
    for (int e = 0; e < 4; ++e) o[e] = T[(tl * 4 + e) * 65 + nl];
    *(f32x4*)(dstate + (size_t)b * 262144 + (size_t)(nb + nl) * 256 + cb + tl * 4) = o;
    u32x2 pk;
    pk[0] = (u32)f2bf(o[0]) | ((u32)f2bf(o[1]) << 16);
    pk[1] = (u32)f2bf(o[2]) | ((u32)f2bf(o[3]) << 16);
    *(u32x2*)(y + (size_t)b * 524288 + (size_t)(nb + nl) * 512 + cb + tl * 4) = pk;
  }
}

// ---------------- K/V projection -------------------------------------------
__global__ __launch_bounds__(256) void k_projkv(
    const u16* __restrict__ y, const u16* __restrict__ wk, const u16* __restrict__ wv,
    const float* __restrict__ bk, const float* __restrict__ bv, u16* __restrict__ kbuf,
    u16* __restrict__ vbuf, int crossmask) {
  int z = blockIdx.z, b = z & 3, isv = z >> 2;
  int srcb = b ^ crossmask;
  const u16* X = y + (size_t)srcb * 524288;
  int tid = threadIdx.x, lane = tid & 63, l4 = lane >> 4, l15 = lane & 15;
  int w = tid >> 6, wm = w >> 1, wn = w & 1;
  f32x4 acc[4][4];
  if (!isv) {  // K: out [n][c']  (A = X, B = Wk')
    int bn = blockIdx.x * 128 + wm * 64, bc = blockIdx.y * 128 + wn * 64;
    gemm_nl<512, 256, 256>(X + (size_t)bn * 512, wk + (size_t)bc * 256, acc, l4, l15);
#pragma unroll
    for (int sm = 0; sm < 4; ++sm)
#pragma unroll
      for (int r = 0; r < 4; ++r) {
        int n = bn + sm * 16 + l4 * 4 + r;
#pragma unroll
        for (int sn = 0; sn < 4; ++sn) {
          int col = bc + sn * 16 + l15;
          float bb = bk[((col & 63) << 2) | (col >> 6)];
          kbuf[(size_t)b * 262144 + (size_t)n * 256 + col] = f2bf(acc[sm][sn][r] + bb);
        }
      }
  } else {  // V: out [c'][n]  (A = Wv', B = X)
    int bc = blockIdx.y * 128 + wm * 64, bn = blockIdx.x * 128 + wn * 64;
    gemm_nl<256, 512, 256>(wv + (size_t)bc * 256, X + (size_t)bn * 512, acc, l4, l15);
#pragma unroll
    for (int sm = 0; sm < 4; ++sm)
#pragma unroll
      for (int r = 0; r < 4; ++r) {
        int co = bc + sm * 16 + l4 * 4 + r;
        float bb = bv[((co & 63) << 2) | (co >> 6)];
#pragma unroll
        for (int sn = 0; sn < 4; ++sn) {
          int n = bn + sn * 16 + l15;
          vbuf[(size_t)b * 262144 + (size_t)co * 1024 + n] = f2bf(acc[sm][sn][r] + bb);
        }
      }
  }
}

// ---------------- fused Q-proj + flash attention ---------------------------
// grid (16 n-tiles of 64, 16 b*h); 4 independent waves, 16 q-rows each.
__global__ __launch_bounds__(256) void k_attn(const u16* __restrict__ y,
                                              const u16* __restrict__ kbuf,
                                              const u16* __restrict__ vbuf,
                                              const u16* __restrict__ wq,
                                              const float* __restrict__ bq,
                                              u16* __restrict__ att) {
  __shared__ char Ps[4][2304];  // per-wave 16 rows x 136B
  const int nb = blockIdx.x * 64;
  const int bh = blockIdx.y, b = bh >> 2, h = bh & 3;
  const int tid = threadIdx.x, w = tid >> 6, lane = tid & 63;
  const int l4 = lane >> 4, l15 = lane & 15;
  char* P = Ps[w];
  const u16* X = y + (size_t)b * 524288 + (size_t)(nb + w * 16) * 512;
  const u16* Wq = wq + h * 64 * 256;

  f32x4 qacc[4];
#pragma unroll
  for (int sn = 0; sn < 4; ++sn) qacc[sn] = (f32x4){0.f, 0.f, 0.f, 0.f};
#pragma unroll 2
  for (int k0 = 0; k0 < 256; k0 += 32) {
    AB af;
    af.q = *(const u32x4*)(X + l15 * 512 + k0 + l4 * 8);
#pragma unroll
    for (int sn = 0; sn < 4; ++sn) {
      AB bf;
      bf.q = *(const u32x4*)(Wq + (sn * 16 + l15) * 256 + k0 + l4 * 8);
      qacc[sn] = __builtin_amdgcn_mfma_f32_16x16x32_bf16(af.s, bf.s, qacc[sn], 0, 0, 0);
    }
  }
#pragma unroll
  for (int sn = 0; sn < 4; ++sn) {
    int hd = sn * 16 + l15;
    float bb = 0.125f * bq[hd * 4 + h];  // scale folded (Wq' pre-scaled)
#pragma unroll
    for (int r = 0; r < 4; ++r)
      *(u16*)(P + (l4 * 4 + r) * 136 + hd * 2) = f2bf(qacc[sn][r] + bb);
  }
  AB qf[2];
#pragma unroll
  for (int ks = 0; ks < 2; ++ks) {
    const char* ra = P + l15 * 136 + ks * 64 + l4 * 16;
    qf[ks].d[0] = *(const u32x2*)ra;
    qf[ks].d[1] = *(const u32x2*)(ra + 8);
  }

  const u16* Kb = kbuf + (size_t)b * 262144 + h * 64;          // (m,hd): m*256+hd
  const u16* Vb = vbuf + (size_t)b * 262144 + (size_t)h * 65536;  // (hd,m): hd*1024+m

  f32x4 oacc[4];
#pragma unroll
  for (int sh = 0; sh < 4; ++sh) oacc[sh] = (f32x4){0.f, 0.f, 0.f, 0.f};
  float mst[4] = {-1e30f, -1e30f, -1e30f, -1e30f};
  float lst[4] = {0.f, 0.f, 0.f, 0.f};

  for (int m0 = 0; m0 < 1024; m0 += 64) {
    f32x4 sa[4];
#pragma unroll
    for (int sm = 0; sm < 4; ++sm) {
      sa[sm] = (f32x4){0.f, 0.f, 0.f, 0.f};
#pragma unroll
      for (int ks = 0; ks < 2; ++ks) {
        AB kf;
        kf.q = *(const u32x4*)(Kb + (size_t)(m0 + sm * 16 + l15) * 256 + ks * 32 + l4 * 8);
        sa[sm] = __builtin_amdgcn_mfma_f32_16x16x32_bf16(qf[ks].s, kf.s, sa[sm], 0, 0, 0);
      }
    }
    float corr[4];
#pragma unroll
    for (int r = 0; r < 4; ++r) {
      float m1 = fmaxf(fmaxf(sa[0][r], sa[1][r]), fmaxf(sa[2][r], sa[3][r]));
#pragma unroll
      for (int dd = 1; dd < 16; dd <<= 1) m1 = fmaxf(m1, __shfl_xor(m1, dd));
      float mnew = fmaxf(mst[r], m1);
      corr[r] = __expf(mst[r] - mnew);
      mst[r] = mnew;
      float rs = 0.f;
#pragma unroll
      for (int sm = 0; sm < 4; ++sm) {
        float pv = __expf(sa[sm][r] - mnew);
        sa[sm][r] = pv;
        rs += pv;
      }
#pragma unroll
      for (int dd = 1; dd < 16; dd <<= 1) rs += __shfl_xor(rs, dd);
      lst[r] = lst[r] * corr[r] + rs;
    }
#pragma unroll
    for (int sh = 0; sh < 4; ++sh)
#pragma unroll
      for (int r = 0; r < 4; ++r) oacc[sh][r] *= corr[r];
#pragma unroll
    for (int sm = 0; sm < 4; ++sm)
#pragma unroll
      for (int r = 0; r < 4; ++r)
        *(u16*)(P + (l4 * 4 + r) * 136 + (sm * 16 + l15) * 2) = f2bf(sa[sm][r]);
#pragma unroll
    for (int ks = 0; ks < 2; ++ks) {
      AB pf;
      const char* ra = P + l15 * 136 + ks * 64 + l4 * 16;
      pf.d[0] = *(const u32x2*)ra;
      pf.d[1] = *(const u32x2*)(ra + 8);
#pragma unroll
      for (int sh = 0; sh < 4; ++sh) {
        AB vf;
        vf.q = *(const u32x4*)(Vb + (size_t)(sh * 16 + l15) * 1024 + m0 + ks * 32 + l4 * 8);
        oacc[sh] = __builtin_amdgcn_mfma_f32_16x16x32_bf16(pf.s, vf.s, oacc[sh], 0, 0, 0);
      }
    }
  }
  float inv[4];
#pragma unroll
  for (int r = 0; r < 4; ++r) inv[r] = 1.f / lst[r];
#pragma unroll
  for (int sh = 0; sh < 4; ++sh)
#pragma unroll
    for (int r = 0; r < 4; ++r) {
      int n = nb + w * 16 + l4 * 4 + r;
      att[(size_t)b * 262144 + (size_t)n * 256 + h * 64 + sh * 16 + l15] =
          f2bf(oacc[sh][r] * inv[r]);
    }
}

// ---------------- merge: y msg half = att @ Wm'^T + bm ---------------------
__global__ __launch_bounds__(256) void k_merge(const u16* __restrict__ att,
                                               const u16* __restrict__ wm,
                                               const float* __restrict__ bm,
                                               u16* __restrict__ y) {
  int b = blockIdx.z;
  int tid = threadIdx.x, lane = tid & 63, l4 = lane >> 4, l15 = lane & 15;
  int w = tid >> 6, wm_ = w >> 1, wn = w & 1;
  int bn = blockIdx.x * 128 + wm_ * 64, bc = blockIdx.y * 128 + wn * 64;
  f32x4 acc[4][4];
  gemm_nl<256, 256, 256>(att + (size_t)b * 262144 + (size_t)bn * 256,
                         wm + (size_t)bc * 256, acc, l4, l15);
#pragma unroll
  for (int sm = 0; sm < 4; ++sm)
#pragma unroll
    for (int r = 0; r < 4; ++r) {
      int n = bn + sm * 16 + l4 * 4 + r;
#pragma unroll
      for (int sn = 0; sn < 4; ++sn) {
        int col = bc + sn * 16 + l15;
        y[(size_t)b * 524288 + (size_t)n * 512 + 256 + col] = f2bf(acc[sm][sn][r] + bm[col]);
      }
    }
}

// ---------------- mlp1: h = relu(sc * (W1 @ y) + sh) -----------------------
__global__ __launch_bounds__(256) void k_mlp1(const u16* __restrict__ y,
                                              const u16* __restrict__ w1,
                                              const float* __restrict__ sc,
                                              const float* __restrict__ sh,
                                              u16* __restrict__ hb) {
  int b = blockIdx.z;
  int tid = threadIdx.x, lane = tid & 63, l4 = lane >> 4, l15 = lane & 15;
  int w = tid >> 6, wm = w >> 1, wn = w & 1;
  int bn = blockIdx.x * 128 + wm * 64, bc = blockIdx.y * 128 + wn * 64;
  f32x4 acc[4][4];
  gemm_nl<512, 512, 512>(y + (size_t)b * 524288 + (size_t)bn * 512,
                         w1 + (size_t)bc * 512, acc, l4, l15);
#pragma unroll
  for (int sm = 0; sm < 4; ++sm)
#pragma unroll
    for (int r = 0; r < 4; ++r) {
      int n = bn + sm * 16 + l4 * 4 + r;
#pragma unroll
      for (int sn = 0; sn < 4; ++sn) {
        int col = bc + sn * 16 + l15;
        float val = fmaxf(sc[col] * acc[sm][sn][r] + sh[col], 0.f);
        hb[(size_t)b * 524288 + (size_t)n * 512 + col] = f2bf(val);
      }
    }
}

// ---------------- mlp2: dstate += W2 @ h + b2 ; y_next ; d_out -------------
__global__ __launch_bounds__(256) void k_mlp2(const u16* __restrict__ hb,
                                              const u16* __restrict__ w2,
                                              const float* __restrict__ b2,
                                              float* __restrict__ dstate,
                                              u16* __restrict__ y,
                                              float* __restrict__ out, int cross, int j) {
  int b = blockIdx.z;
  int tid = threadIdx.x, lane = tid & 63, l4 = lane >> 4, l15 = lane & 15;
  int w = tid >> 6, wm = w >> 1, wn = w & 1;
  int bn = blockIdx.x * 128 + wm * 64, bc = blockIdx.y * 128 + wn * 64;
  f32x4 acc[4][4];
  gemm_nl<512, 512, 512>(hb + (size_t)b * 524288 + (size_t)bn * 512,
                         w2 + (size_t)bc * 512, acc, l4, l15);
  float* ob = out + (size_t)(((b >> 1) * 9 + j) * 2 + (b & 1)) * 262144;
#pragma unroll
  for (int sm = 0; sm < 4; ++sm)
#pragma unroll
    for (int r = 0; r < 4; ++r) {
      int n = bn + sm * 16 + l4 * 4 + r;
#pragma unroll
      for (int sn = 0; sn < 4; ++sn) {
        int col = bc + sn * 16 + l15;
        size_t di = (size_t)b * 262144 + (size_t)n * 256 + col;
        float nv = dstate[di] + acc[sm][sn][r] + b2[col];
        dstate[di] = nv;
        y[(size_t)b * 524288 + (size_t)n * 512 + col] = f2bf(nv);
        if (cross) ob[(size_t)col * 1024 + n] = nv;  // L2 merges per-line
      }
    }
}

// ---------------- host ------------------------------------------------------
extern "C" void kernel_launch(void* const* d_in, const int* in_sizes, int n_in,
                              void* d_out, int out_size, void* d_ws, size_t ws_size,
                              hipStream_t stream) {
  const float* desc0 = (const float*)d_in[0];
  const float* desc1 = (const float*)d_in[1];
  const float* Wq = (const float*)d_in[2];
  const float* bq = (const float*)d_in[3];
  const float* Wk = (const float*)d_in[4];
  const float* bk = (const float*)d_in[5];
  const float* Wv = (const float*)d_in[6];
  const float* bv = (const float*)d_in[7];
  const float* Wm = (const float*)d_in[8];
  const float* bm = (const float*)d_in[9];
  const float* W1 = (const float*)d_in[10];
  const float* b1 = (const float*)d_in[11];
  const float* gamma = (const float*)d_in[12];
  const float* beta = (const float*)d_in[13];
  const float* mu = (const float*)d_in[14];
  const float* var = (const float*)d_in[15];
  const float* W2 = (const float*)d_in[16];
  const float* b2 = (const float*)d_in[17];

  char* ws = (char*)d_ws;
  float* dstate = (float*)ws;                        // 4 MB
  u16* y = (u16*)(ws + ((size_t)4 << 20));           // 4 MB
  u16* kbuf = (u16*)(ws + ((size_t)8 << 20));        // 2 MB
  u16* vbuf = (u16*)(ws + ((size_t)10 << 20));       // 2 MB
  u16* attb = (u16*)(ws + ((size_t)12 << 20));       // 2 MB
  u16* hb = (u16*)(ws + ((size_t)14 << 20));         // 4 MB
  u16* wbf = (u16*)(ws + ((size_t)18 << 20));        // 23.6 MB
  float* scb = (float*)(ws + ((size_t)42 << 20));
  float* shb = (float*)(ws + ((size_t)43 << 20));

  k_setup<<<11556, 256, 0, stream>>>(Wq, Wk, Wv, Wm, W1, W2, gamma, beta, mu, var, b1,
                                     wbf, scb, shb);
  k_init<<<dim3(16, 4, 4), 256, 0, stream>>>(desc0, desc1, dstate, y);

  for (int i = 0; i < 18; ++i) {
    int cross = i & 1;
    const u16* wl = wbf + (size_t)i * 655360;
    k_projkv<<<dim3(8, 2, 8), 256, 0, stream>>>(y, wl + 65536, wl + 131072, bk + i * 256,
                                                bv + i * 256, kbuf, vbuf, cross ? 2 : 0);
    k_attn<<<dim3(16, 16), 256, 0, stream>>>(y, kbuf, vbuf, wl, bq + i * 256, attb);
    k_merge<<<dim3(8, 2, 4), 256, 0, stream>>>(attb, wl + 196608, bm + i * 256, y);
    k_mlp1<<<dim3(8, 4, 4), 256, 0, stream>>>(y, wl + 262144, scb + (size_t)i * 512,
                                              shb + (size_t)i * 512, hb);
    k_mlp2<<<dim3(8, 2, 4), 256, 0, stream>>>(hb, wl + 524288, b2 + i * 256, dstate, y,
                                              (float*)d_out, cross, i >> 1);
  }
}

// Round 3
// 1439.640 us; speedup vs baseline: 1.5608x; 1.4700x over previous
//
#include <hip/hip_runtime.h>
#include <math.h>

// GraphMatcher R3: n-major layout, small-tile high-parallelism GEMMs with
// register double-buffer prefetch; fused QKV projection; flash attention with
// swapped-operand softmax + KV-split-2 (2048 waves) + K prefetch.
//   dstate [4][1024][256] f32 ; y [4][1024][512] bf16 (x | msg)
//   qbuf/kbuf [4][1024][256] bf16 (c'=h*64+hd) ; vbuf [4][256][1024] bf16
//   attb [4096][256] bf16 ; hb [4096][512] bf16

typedef unsigned short u16;
typedef unsigned int u32;
typedef __attribute__((ext_vector_type(4))) unsigned int u32x4;
typedef __attribute__((ext_vector_type(2))) unsigned int u32x2;
typedef __attribute__((ext_vector_type(8))) short short8v;
typedef __attribute__((ext_vector_type(4))) float f32x4;

union AB { u32x4 q; u32x2 d[2]; short8v s; };

__device__ __forceinline__ u16 f2bf(float f) {
  u32 u = __builtin_bit_cast(u32, f);
  u32 r = u + 0x7fffu + ((u >> 16) & 1u);
  return (u16)(r >> 16);
}

// wave tile 32(M)x64(N); block = 2 waves stacked on M -> 64x64.
// A rows M, B rows N, both k-contiguous. 1-step (32k) register lookahead.
template<int LDA, int LDB, int K>
__device__ __forceinline__ void gemm_w(const u16* __restrict__ A, const u16* __restrict__ B,
                                       f32x4 (&acc)[2][4], int l4, int l15) {
  const u16* Ap = A + l15 * LDA + l4 * 8;
  const u16* Bp = B + l15 * LDB + l4 * 8;
#pragma unroll
  for (int a = 0; a < 2; ++a)
#pragma unroll
    for (int c = 0; c < 4; ++c) acc[a][c] = (f32x4){0.f, 0.f, 0.f, 0.f};
  AB a[2][2], b[2][4];
#pragma unroll
  for (int sm = 0; sm < 2; ++sm) a[0][sm].q = *(const u32x4*)(Ap + sm * 16 * LDA);
#pragma unroll
  for (int sn = 0; sn < 4; ++sn) b[0][sn].q = *(const u32x4*)(Bp + sn * 16 * LDB);
#pragma unroll
  for (int kp = 0; kp < K / 32; ++kp) {
    const int cu = kp & 1, nx = cu ^ 1;
    if (kp + 1 < K / 32) {
      const int ko = (kp + 1) * 32;
#pragma unroll
      for (int sm = 0; sm < 2; ++sm) a[nx][sm].q = *(const u32x4*)(Ap + sm * 16 * LDA + ko);
#pragma unroll
      for (int sn = 0; sn < 4; ++sn) b[nx][sn].q = *(const u32x4*)(Bp + sn * 16 * LDB + ko);
    }
#pragma unroll
    for (int sm = 0; sm < 2; ++sm)
#pragma unroll
      for (int sn = 0; sn < 4; ++sn)
        acc[sm][sn] =
            __builtin_amdgcn_mfma_f32_16x16x32_bf16(a[cu][sm].s, b[cu][sn].s, acc[sm][sn], 0, 0, 0);
  }
}

// ---------------- setup (weights cast/permute + BN fold) --------------------
__global__ void k_setup(const float* __restrict__ Wq, const float* __restrict__ Wk,
                        const float* __restrict__ Wv, const float* __restrict__ Wm,
                        const float* __restrict__ W1, const float* __restrict__ W2,
                        const float* __restrict__ g, const float* __restrict__ be,
                        const float* __restrict__ mu, const float* __restrict__ va,
                        const float* __restrict__ b1, u16* __restrict__ wbf,
                        float* __restrict__ sc, float* __restrict__ sh) {
  int bid = blockIdx.x, tid = threadIdx.x;
  if (bid < 4608) {  // Wq/Wk/Wv row-permute (hd*4+h -> h*64+hd); Wm col-permute
    int which = bid / 1152, lb = bid - which * 1152;
    size_t i4 = ((size_t)lb * 256 + tid) * 4;
    int layer = (int)(i4 >> 16), rem = (int)(i4 & 65535);
    int row = rem >> 8, kk = rem & 255;
    const float* src = which == 0 ? Wq : which == 1 ? Wk : which == 2 ? Wv : Wm;
    f32x4 a = *(const f32x4*)(src + i4);
    u16* dl = wbf + (size_t)layer * 655360 + which * 65536;
    if (which < 3) {
      float s = (which == 0) ? 0.125f : 1.0f;
      int rp = ((row & 3) << 6) | (row >> 2);
      u32x2 pk;
      pk[0] = (u32)f2bf(a[0] * s) | ((u32)f2bf(a[1] * s) << 16);
      pk[1] = (u32)f2bf(a[2] * s) | ((u32)f2bf(a[3] * s) << 16);
      *(u32x2*)(dl + rp * 256 + kk) = pk;
    } else {
#pragma unroll
      for (int e = 0; e < 4; ++e) {
        int ci = kk + e, cp = ((ci & 3) << 6) | (ci >> 2);
        dl[row * 256 + cp] = f2bf(a[e]);
      }
    }
  } else if (bid < 9216) {  // W1
    int lb = bid - 4608;
    size_t i4 = ((size_t)lb * 256 + tid) * 4;
    int layer = (int)(i4 >> 18);
    size_t rem = i4 & 262143;
    f32x4 a = *(const f32x4*)(W1 + i4);
    u32x2 pk;
    pk[0] = (u32)f2bf(a[0]) | ((u32)f2bf(a[1]) << 16);
    pk[1] = (u32)f2bf(a[2]) | ((u32)f2bf(a[3]) << 16);
    *(u32x2*)(wbf + (size_t)layer * 655360 + 262144 + rem) = pk;
  } else if (bid < 11520) {  // W2
    int lb = bid - 9216;
    size_t i4 = ((size_t)lb * 256 + tid) * 4;
    int layer = (int)(i4 >> 17);
    size_t rem = i4 & 131071;
    f32x4 a = *(const f32x4*)(W2 + i4);
    u32x2 pk;
    pk[0] = (u32)f2bf(a[0]) | ((u32)f2bf(a[1]) << 16);
    pk[1] = (u32)f2bf(a[2]) | ((u32)f2bf(a[3]) << 16);
    *(u32x2*)(wbf + (size_t)layer * 655360 + 524288 + rem) = pk;
  } else {
    int i = (bid - 11520) * 256 + tid;
    if (i < 9216) {
      float s = g[i] * rsqrtf(va[i] + 1e-5f);
      sc[i] = s;
      sh[i] = s * (b1[i] - mu[i]) + be[i];
    }
  }
}

// ---------------- init: desc [c][n] -> dstate [n][c] f32 + y bf16 ----------
__global__ __launch_bounds__(256) void k_init(const float* __restrict__ d0,
                                              const float* __restrict__ d1,
                                              float* __restrict__ dstate,
                                              u16* __restrict__ y) {
  __shared__ float T[64 * 65];
  int b = blockIdx.z, cb = blockIdx.y * 64, nb = blockIdx.x * 64;
  int t = threadIdx.x, th = t >> 4, tl = t & 15;
  const float* src = (b < 2 ? d0 : d1) + (size_t)(b & 1) * 262144;
#pragma unroll
  for (int it = 0; it < 4; ++it) {
    int cl = it * 16 + th;
    f32x4 v = *(const f32x4*)(src + (size_t)(cb + cl) * 1024 + nb + tl * 4);
#pragma unroll
    for (int e = 0; e < 4; ++e) T[cl * 65 + tl * 4 + e] = v[e];
  }
  __syncthreads();
#pragma unroll
  for (int it = 0; it < 4; ++it) {
    int nl = it * 16 + th;
    f32x4 o;
#pragma unroll
    for (int e = 0; e < 4; ++e) o[e] = T[(tl * 4 + e) * 65 + nl];
    *(f32x4*)(dstate + (size_t)b * 262144 + (size_t)(nb + nl) * 256 + cb + tl * 4) = o;
    u32x2 pk;
    pk[0] = (u32)f2bf(o[0]) | ((u32)f2bf(o[1]) << 16);
    pk[1] = (u32)f2bf(o[2]) | ((u32)f2bf(o[3]) << 16);
    *(u32x2*)(y + (size_t)b * 524288 + (size_t)(nb + nl) * 512 + cb + tl * 4) = pk;
  }
}

// ---------------- fused QKV projection -------------------------------------
// grid (12, 64): bx 0-3 Q, 4-7 K, 8-11 V ; by = (b<<4)|n64tile. 128 threads.
__global__ __launch_bounds__(128) void k_proj(
    const u16* __restrict__ y, const u16* __restrict__ wl, const float* __restrict__ bq,
    const float* __restrict__ bk, const float* __restrict__ bv, u16* __restrict__ qb,
    u16* __restrict__ kb, u16* __restrict__ vb, int crossmask) {
  int bx = blockIdx.x, by = blockIdx.y;
  int tid = threadIdx.x, lane = tid & 63, l4 = lane >> 4, l15 = lane & 15, w = tid >> 6;
  int typ = bx >> 2, ct = bx & 3;
  int b = by >> 4, t64 = by & 15;
  f32x4 acc[2][4];
  if (typ < 2) {  // Q or K: out [n][c']
    int srcb = typ ? (b ^ crossmask) : b;
    const u16* A = y + (size_t)srcb * 524288 + (size_t)(t64 * 64 + w * 32) * 512;
    const u16* B = wl + (typ ? 65536 : 0) + (ct * 64) * 256;
    gemm_w<512, 256, 256>(A, B, acc, l4, l15);
    const float* bias = typ ? bk : bq;
    float bs = typ ? 1.f : 0.125f;
    u16* ob = (typ ? kb : qb) + (size_t)b * 262144;
#pragma unroll
    for (int sm = 0; sm < 2; ++sm)
#pragma unroll
      for (int r = 0; r < 4; ++r) {
        int n = t64 * 64 + w * 32 + sm * 16 + l4 * 4 + r;
#pragma unroll
        for (int sn = 0; sn < 4; ++sn) {
          int c = ct * 64 + sn * 16 + l15;
          float bb = bs * bias[(c & 63) * 4 + (c >> 6)];
          ob[(size_t)n * 256 + c] = f2bf(acc[sm][sn][r] + bb);
        }
      }
  } else {  // V: out [c'][n]  (A = Wv rows c', B = X rows n)
    int srcb = b ^ crossmask;
    const u16* A = wl + 131072 + (size_t)(ct * 64 + w * 32) * 256;
    const u16* B = y + (size_t)srcb * 524288 + (size_t)(t64 * 64) * 512;
    gemm_w<256, 512, 256>(A, B, acc, l4, l15);
    u16* ob = vb + (size_t)b * 262144;
#pragma unroll
    for (int sm = 0; sm < 2; ++sm)
#pragma unroll
      for (int r = 0; r < 4; ++r) {
        int c = ct * 64 + w * 32 + sm * 16 + l4 * 4 + r;
        float bb = bv[(c & 63) * 4 + (c >> 6)];
#pragma unroll
        for (int sn = 0; sn < 4; ++sn) {
          int n = t64 * 64 + sn * 16 + l15;
          ob[(size_t)c * 1024 + n] = f2bf(acc[sm][sn][r] + bb);
        }
      }
  }
}

// ---------------- flash attention, swapped softmax, KV-split-2 -------------
// grid (32 n-tiles of 32, 16 b*h), 256 thr. wave w: rg=w&1 (16 q-rows),
// half=w>>1 (keys [half*512, half*512+512)). Merge halves via LDS at end.
__global__ __launch_bounds__(256) void k_attn(const u16* __restrict__ qbuf,
                                              const u16* __restrict__ kbuf,
                                              const u16* __restrict__ vbuf,
                                              u16* __restrict__ att) {
  __shared__ char Ps[4][2304];
  __shared__ float Ms[2][16], Ls[2][16], Os[2][16][68];
  const int nb = blockIdx.x * 32;
  const int bh = blockIdx.y, b = bh >> 2, h = bh & 3;
  const int tid = threadIdx.x, w = tid >> 6, lane = tid & 63;
  const int l4 = lane >> 4, l15 = lane & 15;
  const int rg = w & 1, half = w >> 1;
  char* P = Ps[w];
  const u16* Qb = qbuf + (size_t)b * 262144 + h * 64;
  const u16* Kb = kbuf + (size_t)b * 262144 + h * 64;
  const u16* Vb = vbuf + (size_t)b * 262144 + (size_t)h * 65536;
  const int qrow = nb + rg * 16;
  AB qf[2];
#pragma unroll
  for (int ks = 0; ks < 2; ++ks)
    qf[ks].q = *(const u32x4*)(Qb + (size_t)(qrow + l15) * 256 + ks * 32 + l4 * 8);

  f32x4 oacc[4];
#pragma unroll
  for (int sh = 0; sh < 4; ++sh) oacc[sh] = (f32x4){0.f, 0.f, 0.f, 0.f};
  float mst = -1e30f, lst = 0.f;
  const int mbase = half * 512;

  AB kf[2][2][4], vf[2][4];
#pragma unroll
  for (int ks = 0; ks < 2; ++ks)
#pragma unroll
    for (int s = 0; s < 4; ++s)
      kf[0][ks][s].q = *(const u32x4*)(Kb + (size_t)(mbase + s * 16 + l15) * 256 + ks * 32 + l4 * 8);

#pragma unroll
  for (int mt = 0; mt < 8; ++mt) {
    const int cu = mt & 1, nx = cu ^ 1;
    const int m0 = mbase + mt * 64;
    // current V (consumed after softmax -> latency hidden)
#pragma unroll
    for (int ks = 0; ks < 2; ++ks)
#pragma unroll
      for (int s = 0; s < 4; ++s)
        vf[ks][s].q = *(const u32x4*)(Vb + (size_t)(s * 16 + l15) * 1024 + m0 + ks * 32 + l4 * 8);
    // next K
    if (mt < 7) {
#pragma unroll
      for (int ks = 0; ks < 2; ++ks)
#pragma unroll
        for (int s = 0; s < 4; ++s)
          kf[nx][ks][s].q =
              *(const u32x4*)(Kb + (size_t)(m0 + 64 + s * 16 + l15) * 256 + ks * 32 + l4 * 8);
    }
    // S^T tile: rows m (A=K), cols n (B=Q); lane: n=l15, m = sm*16+l4*4+r
    f32x4 sa[4];
#pragma unroll
    for (int sm = 0; sm < 4; ++sm) {
      sa[sm] = (f32x4){0.f, 0.f, 0.f, 0.f};
      sa[sm] = __builtin_amdgcn_mfma_f32_16x16x32_bf16(kf[cu][0][sm].s, qf[0].s, sa[sm], 0, 0, 0);
      sa[sm] = __builtin_amdgcn_mfma_f32_16x16x32_bf16(kf[cu][1][sm].s, qf[1].s, sa[sm], 0, 0, 0);
    }
    // softmax over m for this lane's n=l15: 16 in-lane + 2 shfl
    float m1 = fmaxf(fmaxf(fmaxf(sa[0][0], sa[0][1]), fmaxf(sa[0][2], sa[0][3])),
                     fmaxf(fmaxf(sa[1][0], sa[1][1]), fmaxf(sa[1][2], sa[1][3])));
    float m2 = fmaxf(fmaxf(fmaxf(sa[2][0], sa[2][1]), fmaxf(sa[2][2], sa[2][3])),
                     fmaxf(fmaxf(sa[3][0], sa[3][1]), fmaxf(sa[3][2], sa[3][3])));
    m1 = fmaxf(m1, m2);
    m1 = fmaxf(m1, __shfl_xor(m1, 16));
    m1 = fmaxf(m1, __shfl_xor(m1, 32));
    float mnew = fmaxf(mst, m1);
    float corr = __expf(mst - mnew);
    mst = mnew;
    float rs = 0.f;
#pragma unroll
    for (int sm = 0; sm < 4; ++sm)
#pragma unroll
      for (int r = 0; r < 4; ++r) {
        float p = __expf(sa[sm][r] - mnew);
        sa[sm][r] = p;
        rs += p;
      }
    rs += __shfl_xor(rs, 16);
    rs += __shfl_xor(rs, 32);
    lst = lst * corr + rs;
    // rescale O rows (row n_local = l4*4+r needs corr of lane l15=n_local)
#pragma unroll
    for (int r = 0; r < 4; ++r) {
      float cr = __shfl(corr, l4 * 4 + r);
#pragma unroll
      for (int sh = 0; sh < 4; ++sh) oacc[sh][r] *= cr;
    }
    // P^T -> LDS as [n][m]: row l15, 8B per sm
#pragma unroll
    for (int sm = 0; sm < 4; ++sm) {
      u32x2 pk;
      pk[0] = (u32)f2bf(sa[sm][0]) | ((u32)f2bf(sa[sm][1]) << 16);
      pk[1] = (u32)f2bf(sa[sm][2]) | ((u32)f2bf(sa[sm][3]) << 16);
      *(u32x2*)(P + l15 * 136 + (sm * 16 + l4 * 4) * 2) = pk;
    }
    // PV: A=P rows n, k=m ; B=V rows hd, k=m
#pragma unroll
    for (int ks = 0; ks < 2; ++ks) {
      AB pf;
      const char* ra = P + l15 * 136 + ks * 64 + l4 * 16;
      pf.d[0] = *(const u32x2*)ra;
      pf.d[1] = *(const u32x2*)(ra + 8);
#pragma unroll
      for (int sh = 0; sh < 4; ++sh)
        oacc[sh] = __builtin_amdgcn_mfma_f32_16x16x32_bf16(pf.s, vf[ks][sh].s, oacc[sh], 0, 0, 0);
    }
  }
  // merge the two KV halves (waves half==1 publish, half==0 combine+store)
  if (half == 1) {
    Ms[rg][l15] = mst;
    Ls[rg][l15] = lst;
#pragma unroll
    for (int sh = 0; sh < 4; ++sh)
#pragma unroll
      for (int r = 0; r < 4; ++r) Os[rg][l4 * 4 + r][sh * 16 + l15] = oacc[sh][r];
  }
  __syncthreads();
  if (half == 0) {
    float mb = Ms[rg][l15], lb = Ls[rg][l15];
    float M = fmaxf(mst, mb);
    float ea = __expf(mst - M), eb = __expf(mb - M);
    float rl = 1.f / (lst * ea + lb * eb);
    float fa = ea * rl, fb = eb * rl;
#pragma unroll
    for (int r = 0; r < 4; ++r) {
      float far = __shfl(fa, l4 * 4 + r);
      float fbr = __shfl(fb, l4 * 4 + r);
      int n = nb + rg * 16 + l4 * 4 + r;
#pragma unroll
      for (int sh = 0; sh < 4; ++sh) {
        float ov = oacc[sh][r] * far + Os[rg][l4 * 4 + r][sh * 16 + l15] * fbr;
        att[(size_t)b * 262144 + (size_t)n * 256 + h * 64 + sh * 16 + l15] = f2bf(ov);
      }
    }
  }
}

// ---------------- merge GEMM: y msg half ------------------------------------
__global__ __launch_bounds__(128) void k_merge(const u16* __restrict__ att,
                                               const u16* __restrict__ wm,
                                               const float* __restrict__ bm,
                                               u16* __restrict__ y) {
  int tid = threadIdx.x, lane = tid & 63, l4 = lane >> 4, l15 = lane & 15, w = tid >> 6;
  int row0 = blockIdx.y * 64 + w * 32, col0 = blockIdx.x * 64;
  f32x4 acc[2][4];
  gemm_w<256, 256, 256>(att + (size_t)row0 * 256, wm + (size_t)col0 * 256, acc, l4, l15);
#pragma unroll
  for (int sm = 0; sm < 2; ++sm)
#pragma unroll
    for (int r = 0; r < 4; ++r) {
      int n = row0 + sm * 16 + l4 * 4 + r;
#pragma unroll
      for (int sn = 0; sn < 4; ++sn) {
        int c = col0 + sn * 16 + l15;
        y[(size_t)n * 512 + 256 + c] = f2bf(acc[sm][sn][r] + bm[c]);
      }
    }
}

// ---------------- mlp1 ------------------------------------------------------
__global__ __launch_bounds__(128) void k_mlp1(const u16* __restrict__ y,
                                              const u16* __restrict__ w1,
                                              const float* __restrict__ sc,
                                              const float* __restrict__ sh,
                                              u16* __restrict__ hb) {
  int tid = threadIdx.x, lane = tid & 63, l4 = lane >> 4, l15 = lane & 15, w = tid >> 6;
  int row0 = blockIdx.y * 64 + w * 32, col0 = blockIdx.x * 64;
  f32x4 acc[2][4];
  gemm_w<512, 512, 512>(y + (size_t)row0 * 512, w1 + (size_t)col0 * 512, acc, l4, l15);
#pragma unroll
  for (int sm = 0; sm < 2; ++sm)
#pragma unroll
    for (int r = 0; r < 4; ++r) {
      int n = row0 + sm * 16 + l4 * 4 + r;
#pragma unroll
      for (int sn = 0; sn < 4; ++sn) {
        int c = col0 + sn * 16 + l15;
        float v = fmaxf(sc[c] * acc[sm][sn][r] + sh[c], 0.f);
        hb[(size_t)n * 512 + c] = f2bf(v);
      }
    }
}

// ---------------- mlp2 + residual + y_next + d_out --------------------------
__global__ __launch_bounds__(128) void k_mlp2(const u16* __restrict__ hb,
                                              const u16* __restrict__ w2,
                                              const float* __restrict__ b2,
                                              float* __restrict__ dstate,
                                              u16* __restrict__ y,
                                              float* __restrict__ out, int cross, int j) {
  int tid = threadIdx.x, lane = tid & 63, l4 = lane >> 4, l15 = lane & 15, w = tid >> 6;
  int row0 = blockIdx.y * 64 + w * 32, col0 = blockIdx.x * 64;
  f32x4 acc[2][4];
  gemm_w<512, 512, 512>(hb + (size_t)row0 * 512, w2 + (size_t)col0 * 512, acc, l4, l15);
#pragma unroll
  for (int sm = 0; sm < 2; ++sm)
#pragma unroll
    for (int r = 0; r < 4; ++r) {
      int row = row0 + sm * 16 + l4 * 4 + r;
      int b = row >> 10, n = row & 1023;
      float* ob = out + (size_t)(((b >> 1) * 9 + j) * 2 + (b & 1)) * 262144;
#pragma unroll
      for (int sn = 0; sn < 4; ++sn) {
        int c = col0 + sn * 16 + l15;
        size_t di = (size_t)row * 256 + c;
        float nv = dstate[di] + acc[sm][sn][r] + b2[c];
        dstate[di] = nv;
        y[(size_t)row * 512 + c] = f2bf(nv);
        if (cross) ob[(size_t)c * 1024 + n] = nv;
      }
    }
}

// ---------------- host ------------------------------------------------------
extern "C" void kernel_launch(void* const* d_in, const int* in_sizes, int n_in,
                              void* d_out, int out_size, void* d_ws, size_t ws_size,
                              hipStream_t stream) {
  const float* desc0 = (const float*)d_in[0];
  const float* desc1 = (const float*)d_in[1];
  const float* Wq = (const float*)d_in[2];
  const float* bq = (const float*)d_in[3];
  const float* Wk = (const float*)d_in[4];
  const float* bk = (const float*)d_in[5];
  const float* Wv = (const float*)d_in[6];
  const float* bv = (const float*)d_in[7];
  const float* Wm = (const float*)d_in[8];
  const float* bm = (const float*)d_in[9];
  const float* W1 = (const float*)d_in[10];
  const float* b1 = (const float*)d_in[11];
  const float* gamma = (const float*)d_in[12];
  const float* beta = (const float*)d_in[13];
  const float* mu = (const float*)d_in[14];
  const float* var = (const float*)d_in[15];
  const float* W2 = (const float*)d_in[16];
  const float* b2 = (const float*)d_in[17];

  char* ws = (char*)d_ws;
  float* dstate = (float*)ws;                        // 4 MB
  u16* y = (u16*)(ws + ((size_t)4 << 20));           // 4 MB
  u16* qbuf = (u16*)(ws + ((size_t)8 << 20));        // 2 MB
  u16* kbuf = (u16*)(ws + ((size_t)10 << 20));       // 2 MB
  u16* vbuf = (u16*)(ws + ((size_t)12 << 20));       // 2 MB
  u16* attb = (u16*)(ws + ((size_t)14 << 20));       // 2 MB
  u16* hb = (u16*)(ws + ((size_t)16 << 20));         // 4 MB
  u16* wbf = (u16*)(ws + ((size_t)20 << 20));        // 23.6 MB
  float* scb = (float*)(ws + ((size_t)44 << 20));
  float* shb = (float*)(ws + ((size_t)45 << 20));

  k_setup<<<11556, 256, 0, stream>>>(Wq, Wk, Wv, Wm, W1, W2, gamma, beta, mu, var, b1,
                                     wbf, scb, shb);
  k_init<<<dim3(16, 4, 4), 256, 0, stream>>>(desc0, desc1, dstate, y);

  for (int i = 0; i < 18; ++i) {
    int cross = i & 1;
    const u16* wl = wbf + (size_t)i * 655360;
    k_proj<<<dim3(12, 64), 128, 0, stream>>>(y, wl, bq + i * 256, bk + i * 256, bv + i * 256,
                                             qbuf, kbuf, vbuf, cross ? 2 : 0);
    k_attn<<<dim3(32, 16), 256, 0, stream>>>(qbuf, kbuf, vbuf, attb);
    k_merge<<<dim3(4, 64), 128, 0, stream>>>(attb, wl + 196608, bm + i * 256, y);
    k_mlp1<<<dim3(8, 64), 128, 0, stream>>>(y, wl + 262144, scb + (size_t)i * 512,
                                            shb + (size_t)i * 512, hb);
    k_mlp2<<<dim3(4, 64), 128, 0, stream>>>(hb, wl + 524288, b2 + i * 256, dstate, y,
                                            (float*)d_out, cross, i >> 1);
  }
}

// Round 4
// 1407.512 us; speedup vs baseline: 1.5964x; 1.0228x over previous
//
#include <hip/hip_runtime.h>
#include <math.h>

// GraphMatcher R4: 2 kernels per layer.
//  k_attn: flash attention (batch-permute on K/V read side for cross layers)
//  k_post: merge + BN-MLP + residual + NEXT layer's QKV, fused row-locally.
// Layouts: dstate [4096][256] f32 ; y [4096][512] bf16 (x|msg) ;
//  qb/kb [4][1024][256] bf16 (c'=h*64+hd, UNpermuted batch) ; vb [4][256][1024];
//  attb [4096][256] bf16. Weights bf16 packed per layer, QKV rows permuted,
//  0.125 folded into Wq/bq.

typedef unsigned short u16;
typedef unsigned int u32;
typedef __attribute__((ext_vector_type(4))) unsigned int u32x4;
typedef __attribute__((ext_vector_type(2))) unsigned int u32x2;
typedef __attribute__((ext_vector_type(8))) short short8v;
typedef __attribute__((ext_vector_type(4))) float f32x4;

union AB { u32x4 q; u32x2 d[2]; short8v s; };

__device__ __forceinline__ u16 f2bf(float f) {
  u32 u = __builtin_bit_cast(u32, f);
  u32 r = u + 0x7fffu + ((u >> 16) & 1u);
  return (u16)(r >> 16);
}

// ---- M=16 GEMM cores: A rows l15-indexed k-contig; B rows pre-offset ptrs.
// mm16g: A from global. mm16l: A from LDS tile [16][512] bf16, XOR-swizzled.
template<int SN, int NK>
__device__ __forceinline__ void mm16g(const u16* __restrict__ Ar,
                                      const u16* const (&Br)[SN], f32x4 (&acc)[SN]) {
#pragma unroll
  for (int s = 0; s < SN; ++s) acc[s] = (f32x4){0.f, 0.f, 0.f, 0.f};
  AB a[2], b[2][SN];
  a[0].q = *(const u32x4*)(Ar);
#pragma unroll
  for (int s = 0; s < SN; ++s) b[0][s].q = *(const u32x4*)(Br[s]);
#pragma unroll
  for (int kp = 0; kp < NK; ++kp) {
    const int cu = kp & 1, nx = cu ^ 1;
    if (kp + 1 < NK) {
      a[nx].q = *(const u32x4*)(Ar + (kp + 1) * 32);
#pragma unroll
      for (int s = 0; s < SN; ++s) b[nx][s].q = *(const u32x4*)(Br[s] + (kp + 1) * 32);
    }
#pragma unroll
    for (int s = 0; s < SN; ++s)
      acc[s] = __builtin_amdgcn_mfma_f32_16x16x32_bf16(a[cu].s, b[cu][s].s, acc[s], 0, 0, 0);
  }
}

template<int SN, int NK>
__device__ __forceinline__ void mm16l(const char* __restrict__ lds, int l4, int l15,
                                      const u16* const (&Br)[SN], f32x4 (&acc)[SN]) {
#pragma unroll
  for (int s = 0; s < SN; ++s) acc[s] = (f32x4){0.f, 0.f, 0.f, 0.f};
  const int ab = l15 * 1024 + l4 * 16, ax = (l15 & 7) << 4;
  AB a[2], b[2][SN];
  a[0].q = *(const u32x4*)(lds + (ab ^ ax));
#pragma unroll
  for (int s = 0; s < SN; ++s) b[0][s].q = *(const u32x4*)(Br[s]);
#pragma unroll
  for (int kp = 0; kp < NK; ++kp) {
    const int cu = kp & 1, nx = cu ^ 1;
    if (kp + 1 < NK) {
      a[nx].q = *(const u32x4*)(lds + ((ab + (kp + 1) * 64) ^ ax));
#pragma unroll
      for (int s = 0; s < SN; ++s) b[nx][s].q = *(const u32x4*)(Br[s] + (kp + 1) * 32);
    }
#pragma unroll
    for (int s = 0; s < SN; ++s)
      acc[s] = __builtin_amdgcn_mfma_f32_16x16x32_bf16(a[cu].s, b[cu][s].s, acc[s], 0, 0, 0);
  }
}

// ---------------- setup: weight cast/permute + BN fold ---------------------
__global__ void k_setup(const float* __restrict__ Wq, const float* __restrict__ Wk,
                        const float* __restrict__ Wv, const float* __restrict__ Wm,
                        const float* __restrict__ W1, const float* __restrict__ W2,
                        const float* __restrict__ g, const float* __restrict__ be,
                        const float* __restrict__ mu, const float* __restrict__ va,
                        const float* __restrict__ b1, u16* __restrict__ wbf,
                        float* __restrict__ sc, float* __restrict__ sh) {
  int bid = blockIdx.x, tid = threadIdx.x;
  if (bid < 4608) {
    int which = bid / 1152, lb = bid - which * 1152;
    size_t i4 = ((size_t)lb * 256 + tid) * 4;
    int layer = (int)(i4 >> 16), rem = (int)(i4 & 65535);
    int row = rem >> 8, kk = rem & 255;
    const float* src = which == 0 ? Wq : which == 1 ? Wk : which == 2 ? Wv : Wm;
    f32x4 a = *(const f32x4*)(src + i4);
    u16* dl = wbf + (size_t)layer * 655360 + which * 65536;
    if (which < 3) {
      float s = (which == 0) ? 0.125f : 1.0f;
      int rp = ((row & 3) << 6) | (row >> 2);
      u32x2 pk;
      pk[0] = (u32)f2bf(a[0] * s) | ((u32)f2bf(a[1] * s) << 16);
      pk[1] = (u32)f2bf(a[2] * s) | ((u32)f2bf(a[3] * s) << 16);
      *(u32x2*)(dl + rp * 256 + kk) = pk;
    } else {
#pragma unroll
      for (int e = 0; e < 4; ++e) {
        int ci = kk + e, cp = ((ci & 3) << 6) | (ci >> 2);
        dl[row * 256 + cp] = f2bf(a[e]);
      }
    }
  } else if (bid < 9216) {
    int lb = bid - 4608;
    size_t i4 = ((size_t)lb * 256 + tid) * 4;
    int layer = (int)(i4 >> 18);
    size_t rem = i4 & 262143;
    f32x4 a = *(const f32x4*)(W1 + i4);
    u32x2 pk;
    pk[0] = (u32)f2bf(a[0]) | ((u32)f2bf(a[1]) << 16);
    pk[1] = (u32)f2bf(a[2]) | ((u32)f2bf(a[3]) << 16);
    *(u32x2*)(wbf + (size_t)layer * 655360 + 262144 + rem) = pk;
  } else if (bid < 11520) {
    int lb = bid - 9216;
    size_t i4 = ((size_t)lb * 256 + tid) * 4;
    int layer = (int)(i4 >> 17);
    size_t rem = i4 & 131071;
    f32x4 a = *(const f32x4*)(W2 + i4);
    u32x2 pk;
    pk[0] = (u32)f2bf(a[0]) | ((u32)f2bf(a[1]) << 16);
    pk[1] = (u32)f2bf(a[2]) | ((u32)f2bf(a[3]) << 16);
    *(u32x2*)(wbf + (size_t)layer * 655360 + 524288 + rem) = pk;
  } else {
    int i = (bid - 11520) * 256 + tid;
    if (i < 9216) {
      float s = g[i] * rsqrtf(va[i] + 1e-5f);
      sc[i] = s;
      sh[i] = s * (b1[i] - mu[i]) + be[i];
    }
  }
}

// ---------------- init: desc [c][n] -> dstate [n][c] f32 + y bf16 ----------
__global__ __launch_bounds__(256) void k_init(const float* __restrict__ d0,
                                              const float* __restrict__ d1,
                                              float* __restrict__ dstate,
                                              u16* __restrict__ y) {
  __shared__ float T[64 * 65];
  int b = blockIdx.z, cb = blockIdx.y * 64, nb = blockIdx.x * 64;
  int t = threadIdx.x, th = t >> 4, tl = t & 15;
  const float* src = (b < 2 ? d0 : d1) + (size_t)(b & 1) * 262144;
#pragma unroll
  for (int it = 0; it < 4; ++it) {
    int cl = it * 16 + th;
    f32x4 v = *(const f32x4*)(src + (size_t)(cb + cl) * 1024 + nb + tl * 4);
#pragma unroll
    for (int e = 0; e < 4; ++e) T[cl * 65 + tl * 4 + e] = v[e];
  }
  __syncthreads();
#pragma unroll
  for (int it = 0; it < 4; ++it) {
    int nl = it * 16 + th;
    f32x4 o;
#pragma unroll
    for (int e = 0; e < 4; ++e) o[e] = T[(tl * 4 + e) * 65 + nl];
    *(f32x4*)(dstate + (size_t)b * 262144 + (size_t)(nb + nl) * 256 + cb + tl * 4) = o;
    u32x2 pk;
    pk[0] = (u32)f2bf(o[0]) | ((u32)f2bf(o[1]) << 16);
    pk[1] = (u32)f2bf(o[2]) | ((u32)f2bf(o[3]) << 16);
    *(u32x2*)(y + (size_t)b * 524288 + (size_t)(nb + nl) * 512 + cb + tl * 4) = pk;
  }
}

// ---------------- QKV epilogue (shared by k_qkv0 and k_post stage4) --------
__device__ __forceinline__ void qkv_epilogue(f32x4 (&acc)[6], const int (&ty)[6],
                                             const int (&cc)[6], int b, int nb0, int l4,
                                             int l15, const float* bqn, const float* bkn,
                                             const float* bvn, u16* qb, u16* kb, u16* vb) {
#pragma unroll
  for (int s = 0; s < 6; ++s) {
    int c = cc[s] + l15;
    int borig = ((c & 63) << 2) | (c >> 6);
    if (ty[s] == 0) {
      float bb = 0.125f * bqn[borig];
#pragma unroll
      for (int r = 0; r < 4; ++r)
        qb[(size_t)b * 262144 + (size_t)(nb0 + l4 * 4 + r) * 256 + c] = f2bf(acc[s][r] + bb);
    } else if (ty[s] == 1) {
      float bb = bkn[borig];
#pragma unroll
      for (int r = 0; r < 4; ++r)
        kb[(size_t)b * 262144 + (size_t)(nb0 + l4 * 4 + r) * 256 + c] = f2bf(acc[s][r] + bb);
    } else {
      float bb = bvn[borig];
      u32x2 pk;
      pk[0] = (u32)f2bf(acc[s][0] + bb) | ((u32)f2bf(acc[s][1] + bb) << 16);
      pk[1] = (u32)f2bf(acc[s][2] + bb) | ((u32)f2bf(acc[s][3] + bb) << 16);
      *(u32x2*)(vb + (size_t)b * 262144 + (size_t)c * 1024 + nb0 + l4 * 4) = pk;
    }
  }
}

// ---------------- layer-0 QKV ----------------------------------------------
__global__ __launch_bounds__(512, 2) void k_qkv0(const u16* __restrict__ y,
                                                 const u16* __restrict__ wln,
                                                 const float* __restrict__ bqn,
                                                 const float* __restrict__ bkn,
                                                 const float* __restrict__ bvn,
                                                 u16* __restrict__ qb, u16* __restrict__ kb,
                                                 u16* __restrict__ vb) {
  const int row0 = blockIdx.x * 16, b = row0 >> 10, nb0 = row0 & 1023;
  const int tid = threadIdx.x, w = tid >> 6, lane = tid & 63;
  const int l4 = lane >> 4, l15 = lane & 15;
  const u16* Ar = y + (size_t)(row0 + l15) * 512 + l4 * 8;
  const u16* Br[6];
  f32x4 acc[6];
  int ty[6], cc[6];
#pragma unroll
  for (int s = 0; s < 6; ++s) {
    int gc = w * 96 + s * 16;
    ty[s] = gc >> 8;
    cc[s] = gc & 255;
    Br[s] = wln + ty[s] * 65536 + (size_t)(cc[s] + l15) * 256 + l4 * 8;
  }
  mm16g<6, 8>(Ar, Br, acc);
  qkv_epilogue(acc, ty, cc, b, nb0, l4, l15, bqn, bkn, bvn, qb, kb, vb);
}

// ---------------- flash attention ------------------------------------------
__global__ __launch_bounds__(256) void k_attn(const u16* __restrict__ qbuf,
                                              const u16* __restrict__ kbuf,
                                              const u16* __restrict__ vbuf,
                                              u16* __restrict__ att, int crossmask) {
  __shared__ char Ps[4][2304];
  __shared__ float Ms[2][16], Ls[2][16], Os[2][16][68];
  const int nb = blockIdx.x * 32;
  const int bh = blockIdx.y, b = bh >> 2, h = bh & 3;
  const int srcb = b ^ crossmask;
  const int tid = threadIdx.x, w = tid >> 6, lane = tid & 63;
  const int l4 = lane >> 4, l15 = lane & 15;
  const int rg = w & 1, half = w >> 1;
  char* P = Ps[w];
  const u16* Qb = qbuf + (size_t)b * 262144 + h * 64;
  const u16* Kb = kbuf + (size_t)srcb * 262144 + h * 64;
  const u16* Vb = vbuf + (size_t)srcb * 262144 + (size_t)h * 65536;
  const int qrow = nb + rg * 16;
  AB qf[2];
#pragma unroll
  for (int ks = 0; ks < 2; ++ks)
    qf[ks].q = *(const u32x4*)(Qb + (size_t)(qrow + l15) * 256 + ks * 32 + l4 * 8);

  f32x4 oacc[4];
#pragma unroll
  for (int sh = 0; sh < 4; ++sh) oacc[sh] = (f32x4){0.f, 0.f, 0.f, 0.f};
  float mst = -1e30f, lst = 0.f;
  const int mbase = half * 512;

  AB kf[2][2][4], vf[2][4];
#pragma unroll
  for (int ks = 0; ks < 2; ++ks)
#pragma unroll
    for (int s = 0; s < 4; ++s)
      kf[0][ks][s].q =
          *(const u32x4*)(Kb + (size_t)(mbase + s * 16 + l15) * 256 + ks * 32 + l4 * 8);

#pragma unroll
  for (int mt = 0; mt < 8; ++mt) {
    const int cu = mt & 1, nx = cu ^ 1;
    const int m0 = mbase + mt * 64;
#pragma unroll
    for (int ks = 0; ks < 2; ++ks)
#pragma unroll
      for (int s = 0; s < 4; ++s)
        vf[ks][s].q =
            *(const u32x4*)(Vb + (size_t)(s * 16 + l15) * 1024 + m0 + ks * 32 + l4 * 8);
    if (mt < 7) {
#pragma unroll
      for (int ks = 0; ks < 2; ++ks)
#pragma unroll
        for (int s = 0; s < 4; ++s)
          kf[nx][ks][s].q =
              *(const u32x4*)(Kb + (size_t)(m0 + 64 + s * 16 + l15) * 256 + ks * 32 + l4 * 8);
    }
    f32x4 sa[4];
#pragma unroll
    for (int sm = 0; sm < 4; ++sm) {
      sa[sm] = (f32x4){0.f, 0.f, 0.f, 0.f};
      sa[sm] = __builtin_amdgcn_mfma_f32_16x16x32_bf16(kf[cu][0][sm].s, qf[0].s, sa[sm], 0, 0, 0);
      sa[sm] = __builtin_amdgcn_mfma_f32_16x16x32_bf16(kf[cu][1][sm].s, qf[1].s, sa[sm], 0, 0, 0);
    }
    float m1 = fmaxf(fmaxf(fmaxf(sa[0][0], sa[0][1]), fmaxf(sa[0][2], sa[0][3])),
                     fmaxf(fmaxf(sa[1][0], sa[1][1]), fmaxf(sa[1][2], sa[1][3])));
    float m2 = fmaxf(fmaxf(fmaxf(sa[2][0], sa[2][1]), fmaxf(sa[2][2], sa[2][3])),
                     fmaxf(fmaxf(sa[3][0], sa[3][1]), fmaxf(sa[3][2], sa[3][3])));
    m1 = fmaxf(m1, m2);
    m1 = fmaxf(m1, __shfl_xor(m1, 16));
    m1 = fmaxf(m1, __shfl_xor(m1, 32));
    float mnew = fmaxf(mst, m1);
    float corr = __expf(mst - mnew);
    mst = mnew;
    float rs = 0.f;
#pragma unroll
    for (int sm = 0; sm < 4; ++sm)
#pragma unroll
      for (int r = 0; r < 4; ++r) {
        float p = __expf(sa[sm][r] - mnew);
        sa[sm][r] = p;
        rs += p;
      }
    rs += __shfl_xor(rs, 16);
    rs += __shfl_xor(rs, 32);
    lst = lst * corr + rs;
#pragma unroll
    for (int r = 0; r < 4; ++r) {
      float cr = __shfl(corr, l4 * 4 + r);
#pragma unroll
      for (int sh = 0; sh < 4; ++sh) oacc[sh][r] *= cr;
    }
#pragma unroll
    for (int sm = 0; sm < 4; ++sm) {
      u32x2 pk;
      pk[0] = (u32)f2bf(sa[sm][0]) | ((u32)f2bf(sa[sm][1]) << 16);
      pk[1] = (u32)f2bf(sa[sm][2]) | ((u32)f2bf(sa[sm][3]) << 16);
      *(u32x2*)(P + l15 * 136 + (sm * 16 + l4 * 4) * 2) = pk;
    }
#pragma unroll
    for (int ks = 0; ks < 2; ++ks) {
      AB pf;
      const char* ra = P + l15 * 136 + ks * 64 + l4 * 16;
      pf.d[0] = *(const u32x2*)ra;
      pf.d[1] = *(const u32x2*)(ra + 8);
#pragma unroll
      for (int sh = 0; sh < 4; ++sh)
        oacc[sh] = __builtin_amdgcn_mfma_f32_16x16x32_bf16(pf.s, vf[ks][sh].s, oacc[sh], 0, 0, 0);
    }
  }
  if (half == 1) {
    Ms[rg][l15] = mst;
    Ls[rg][l15] = lst;
#pragma unroll
    for (int sh = 0; sh < 4; ++sh)
#pragma unroll
      for (int r = 0; r < 4; ++r) Os[rg][l4 * 4 + r][sh * 16 + l15] = oacc[sh][r];
  }
  __syncthreads();
  if (half == 0) {
    float mb = Ms[rg][l15], lb = Ls[rg][l15];
    float M = fmaxf(mst, mb);
    float ea = __expf(mst - M), eb = __expf(mb - M);
    float rl = 1.f / (lst * ea + lb * eb);
    float fa = ea * rl, fb = eb * rl;
#pragma unroll
    for (int r = 0; r < 4; ++r) {
      float far = __shfl(fa, l4 * 4 + r);
      float fbr = __shfl(fb, l4 * 4 + r);
      int n = nb + rg * 16 + l4 * 4 + r;
#pragma unroll
      for (int sh = 0; sh < 4; ++sh) {
        float ov = oacc[sh][r] * far + Os[rg][l4 * 4 + r][sh * 16 + l15] * fbr;
        att[(size_t)b * 262144 + (size_t)n * 256 + h * 64 + sh * 16 + l15] = f2bf(ov);
      }
    }
  }
}

// ---------------- fused post: merge + mlp + residual + next QKV -------------
__global__ __launch_bounds__(512, 2) void k_post(
    const u16* __restrict__ att, const u16* __restrict__ wl, const u16* __restrict__ wln,
    const float* __restrict__ bm, const float* __restrict__ sc, const float* __restrict__ sh,
    const float* __restrict__ b2, const float* __restrict__ bqn,
    const float* __restrict__ bkn, const float* __restrict__ bvn,
    float* __restrict__ dstate, u16* __restrict__ y, u16* __restrict__ qb,
    u16* __restrict__ kb, u16* __restrict__ vb, float* __restrict__ out, int cross, int j,
    int last) {
  __shared__ char yT[16 * 1024];  // [16 rows][512 ch] bf16, XOR-swizzled
  __shared__ char hT[16 * 1024];
  const int row0 = blockIdx.x * 16, b = row0 >> 10, nb0 = row0 & 1023;
  const int tid = threadIdx.x, w = tid >> 6, lane = tid & 63;
  const int l4 = lane >> 4, l15 = lane & 15;

  {  // stage x-half of yT from global y (1 x 16B chunk per thread)
    int rr = tid >> 5, ch = tid & 31;
    u32x4 v = *(const u32x4*)(y + (size_t)(row0 + rr) * 512 + ch * 8);
    *(u32x4*)(yT + ((rr * 1024 + ch * 16) ^ ((rr & 7) << 4))) = v;
  }
  {  // stage1: msg = att @ Wm^T + bm -> yT[.,256:512]
    const u16* Ar = att + (size_t)(row0 + l15) * 256 + l4 * 8;
    const u16* Wm = wl + 196608;
    const u16* Br[2];
    f32x4 acc[2];
#pragma unroll
    for (int s = 0; s < 2; ++s) Br[s] = Wm + (size_t)(w * 32 + s * 16 + l15) * 256 + l4 * 8;
    mm16g<2, 8>(Ar, Br, acc);
#pragma unroll
    for (int s = 0; s < 2; ++s) {
      int c = w * 32 + s * 16 + l15;
      float bb = bm[c];
#pragma unroll
      for (int r = 0; r < 4; ++r) {
        int rw = l4 * 4 + r;
        *(u16*)(yT + ((rw * 1024 + (256 + c) * 2) ^ ((rw & 7) << 4))) = f2bf(acc[s][r] + bb);
      }
    }
  }
  __syncthreads();
  {  // stage2: h = relu(sc*(W1 y)+sh) -> hT
    const u16* W1 = wl + 262144;
    const u16* Br[4];
    f32x4 acc[4];
#pragma unroll
    for (int s = 0; s < 4; ++s) Br[s] = W1 + (size_t)(w * 64 + s * 16 + l15) * 512 + l4 * 8;
    mm16l<4, 16>(yT, l4, l15, Br, acc);
#pragma unroll
    for (int s = 0; s < 4; ++s) {
      int c = w * 64 + s * 16 + l15;
      float s_ = sc[c], t_ = sh[c];
#pragma unroll
      for (int r = 0; r < 4; ++r) {
        int rw = l4 * 4 + r;
        *(u16*)(hT + ((rw * 1024 + c * 2) ^ ((rw & 7) << 4))) =
            f2bf(fmaxf(s_ * acc[s][r] + t_, 0.f));
      }
    }
  }
  __syncthreads();
  {  // stage3: delta = W2 h + b2; dstate += ; y_next x-half; out (cross)
    const u16* W2 = wl + 524288;
    const u16* Br[2];
    f32x4 acc[2];
#pragma unroll
    for (int s = 0; s < 2; ++s) Br[s] = W2 + (size_t)(w * 32 + s * 16 + l15) * 512 + l4 * 8;
    mm16l<2, 16>(hT, l4, l15, Br, acc);
    float* ob = out + (size_t)(((b >> 1) * 9 + j) * 2 + (b & 1)) * 262144;
#pragma unroll
    for (int s = 0; s < 2; ++s) {
      int c = w * 32 + s * 16 + l15;
      float bb = b2[c];
#pragma unroll
      for (int r = 0; r < 4; ++r) {
        int rw = l4 * 4 + r;
        size_t di = (size_t)(row0 + rw) * 256 + c;
        float nv = dstate[di] + acc[s][r] + bb;
        dstate[di] = nv;
        u16 bv16 = f2bf(nv);
        y[(size_t)(row0 + rw) * 512 + c] = bv16;
        *(u16*)(yT + ((rw * 1024 + c * 2) ^ ((rw & 7) << 4))) = bv16;
        if (cross) ob[(size_t)c * 1024 + nb0 + rw] = nv;
      }
    }
  }
  if (last) return;
  __syncthreads();
  {  // stage4: next-layer QKV from yT x-half
    const u16* Br[6];
    f32x4 acc[6];
    int ty[6], cc[6];
#pragma unroll
    for (int s = 0; s < 6; ++s) {
      int gc = w * 96 + s * 16;
      ty[s] = gc >> 8;
      cc[s] = gc & 255;
      Br[s] = wln + ty[s] * 65536 + (size_t)(cc[s] + l15) * 256 + l4 * 8;
    }
    mm16l<6, 8>(yT, l4, l15, Br, acc);
    qkv_epilogue(acc, ty, cc, b, nb0, l4, l15, bqn, bkn, bvn, qb, kb, vb);
  }
}

// ---------------- host ------------------------------------------------------
extern "C" void kernel_launch(void* const* d_in, const int* in_sizes, int n_in,
                              void* d_out, int out_size, void* d_ws, size_t ws_size,
                              hipStream_t stream) {
  const float* desc0 = (const float*)d_in[0];
  const float* desc1 = (const float*)d_in[1];
  const float* Wq = (const float*)d_in[2];
  const float* bq = (const float*)d_in[3];
  const float* Wk = (const float*)d_in[4];
  const float* bk = (const float*)d_in[5];
  const float* Wv = (const float*)d_in[6];
  const float* bv = (const float*)d_in[7];
  const float* Wm = (const float*)d_in[8];
  const float* bm = (const float*)d_in[9];
  const float* W1 = (const float*)d_in[10];
  const float* b1 = (const float*)d_in[11];
  const float* gamma = (const float*)d_in[12];
  const float* beta = (const float*)d_in[13];
  const float* mu = (const float*)d_in[14];
  const float* var = (const float*)d_in[15];
  const float* W2 = (const float*)d_in[16];
  const float* b2 = (const float*)d_in[17];

  char* ws = (char*)d_ws;
  float* dstate = (float*)ws;                   // 4 MB
  u16* y = (u16*)(ws + ((size_t)4 << 20));      // 4 MB
  u16* qb = (u16*)(ws + ((size_t)8 << 20));     // 2 MB
  u16* kb = (u16*)(ws + ((size_t)10 << 20));    // 2 MB
  u16* vb = (u16*)(ws + ((size_t)12 << 20));    // 2 MB
  u16* attb = (u16*)(ws + ((size_t)14 << 20));  // 2 MB
  u16* wbf = (u16*)(ws + ((size_t)16 << 20));   // 23.6 MB
  float* scb = (float*)(ws + ((size_t)40 << 20));
  float* shb = (float*)(ws + ((size_t)41 << 20));

  k_setup<<<11556, 256, 0, stream>>>(Wq, Wk, Wv, Wm, W1, W2, gamma, beta, mu, var, b1,
                                     wbf, scb, shb);
  k_init<<<dim3(16, 4, 4), 256, 0, stream>>>(desc0, desc1, dstate, y);
  k_qkv0<<<256, 512, 0, stream>>>(y, wbf, bq, bk, bv, qb, kb, vb);

  for (int i = 0; i < 18; ++i) {
    int cross = i & 1;
    const u16* wl = wbf + (size_t)i * 655360;
    int nl = (i < 17) ? i + 1 : 0;
    const u16* wln = wbf + (size_t)nl * 655360;
    k_attn<<<dim3(32, 16), 256, 0, stream>>>(qb, kb, vb, attb, cross ? 2 : 0);
    k_post<<<256, 512, 0, stream>>>(attb, wl, wln, bm + i * 256, scb + (size_t)i * 512,
                                    shb + (size_t)i * 512, b2 + i * 256, bq + nl * 256,
                                    bk + nl * 256, bv + nl * 256, dstate, y, qb, kb, vb,
                                    (float*)d_out, cross, i >> 1, i == 17);
  }
}

// Round 5
// 955.424 us; speedup vs baseline: 2.3518x; 1.4732x over previous
//
#include <hip/hip_runtime.h>
#include <math.h>

// GraphMatcher R5: LDS-staged, bandwidth-bound fused kernels.
//  k_attn: flash attn, 64 q-rows/block, 8 waves (4 q-subtiles x 2 KV halves),
//          K/V block-cooperatively staged thru swizzled LDS double-buffers.
//  k_post: merge + BN-MLP + residual + next QKV; weights streamed thru a
//          double-buffered LDS slab (reg-staged, 32-k slabs), 16 waves.
// Layouts: dstate [4096][256] f32 ; y [4096][512] bf16 (x-half live) ;
//  qb/kb [4][1024][256] bf16 (c'=h*64+hd) ; vb [4][256][1024] bf16 ;
//  attb [4096][256] bf16. QKV weight rows permuted hd*4+h -> h*64+hd,
//  0.125 folded into Wq/bq; K/V batch-permute applied at attn read side.

typedef unsigned short u16;
typedef unsigned int u32;
typedef __attribute__((ext_vector_type(4))) unsigned int u32x4;
typedef __attribute__((ext_vector_type(2))) unsigned int u32x2;
typedef __attribute__((ext_vector_type(8))) short short8v;
typedef __attribute__((ext_vector_type(4))) float f32x4;

union AB { u32x4 q; u32x2 d[2]; short8v s; };

__device__ __forceinline__ u16 f2bf(float f) {
  u32 u = __builtin_bit_cast(u32, f);
  u32 r = u + 0x7fffu + ((u >> 16) & 1u);
  return (u16)(r >> 16);
}

// ---- M=16 GEMM, A rows l15-indexed k-contig from global (k_qkv0 only) ----
template<int SN, int NK>
__device__ __forceinline__ void mm16g(const u16* __restrict__ Ar,
                                      const u16* const (&Br)[SN], f32x4 (&acc)[SN]) {
#pragma unroll
  for (int s = 0; s < SN; ++s) acc[s] = (f32x4){0.f, 0.f, 0.f, 0.f};
  AB a[2], b[2][SN];
  a[0].q = *(const u32x4*)(Ar);
#pragma unroll
  for (int s = 0; s < SN; ++s) b[0][s].q = *(const u32x4*)(Br[s]);
#pragma unroll
  for (int kp = 0; kp < NK; ++kp) {
    const int cu = kp & 1, nx = cu ^ 1;
    if (kp + 1 < NK) {
      a[nx].q = *(const u32x4*)(Ar + (kp + 1) * 32);
#pragma unroll
      for (int s = 0; s < SN; ++s) b[nx][s].q = *(const u32x4*)(Br[s] + (kp + 1) * 32);
    }
#pragma unroll
    for (int s = 0; s < SN; ++s)
      acc[s] = __builtin_amdgcn_mfma_f32_16x16x32_bf16(a[cu].s, b[cu][s].s, acc[s], 0, 0, 0);
  }
}

// ---- k_post core: C[16][N] = A[16][Kd] * W[N][Kd]^T, W thru LDS dbuf ------
// 1024 threads. Wb: 2 buffers of N*64 B. A from swizzled LDS (yT/hT) or global.
template<int N, int Kd, int SN, bool ALDS>
__device__ __forceinline__ void stageW(const u16* __restrict__ W, char* __restrict__ Wb,
                                       const char* __restrict__ Alds,
                                       const u16* __restrict__ Ag, f32x4 (&acc)[SN],
                                       int tid, int w, int l4, int l15) {
  constexpr int NS = Kd / 32;
  constexpr int CH = (N * 4) / 1024;  // 16B chunks per thread per slab
  const int colb = tid >> 2, jb = (tid & 3) * 16;
  u32x4 st[2][CH];
#pragma unroll
  for (int c = 0; c < CH; ++c) {
    int col = colb + c * 256;
    st[0][c] = *(const u32x4*)((const char*)(W + (size_t)col * Kd) + jb);
  }
#pragma unroll
  for (int c = 0; c < CH; ++c) {
    int col = colb + c * 256;
    *(u32x4*)(Wb + col * 64 + (jb ^ ((col & 3) << 4))) = st[0][c];
  }
#pragma unroll
  for (int s = 0; s < SN; ++s) acc[s] = (f32x4){0.f, 0.f, 0.f, 0.f};
  __syncthreads();
#pragma unroll
  for (int slab = 0; slab < NS; ++slab) {
    const int cur = slab & 1, nx = cur ^ 1;
    if (slab + 1 < NS) {
#pragma unroll
      for (int c = 0; c < CH; ++c) {
        int col = colb + c * 256;
        st[nx][c] =
            *(const u32x4*)((const char*)(W + (size_t)col * Kd + (slab + 1) * 32) + jb);
      }
    }
    AB af;
    if constexpr (ALDS) {
      int ab = l15 * 1024 + slab * 64 + l4 * 16;
      af.q = *(const u32x4*)(Alds + (ab ^ ((l15 & 7) << 4)));
    } else {
      af.q = *(const u32x4*)(Ag + slab * 32);
    }
    const char* rb = Wb + cur * (N * 64);
#pragma unroll
    for (int s = 0; s < SN; ++s) {
      int col = w * (16 * SN) + s * 16 + l15;
      AB bf;
      bf.q = *(const u32x4*)(rb + col * 64 + ((l4 * 16) ^ ((col & 3) << 4)));
      acc[s] = __builtin_amdgcn_mfma_f32_16x16x32_bf16(af.s, bf.s, acc[s], 0, 0, 0);
    }
    if (slab + 1 < NS) {
      char* wb2 = Wb + nx * (N * 64);
#pragma unroll
      for (int c = 0; c < CH; ++c) {
        int col = colb + c * 256;
        *(u32x4*)(wb2 + col * 64 + (jb ^ ((col & 3) << 4))) = st[nx][c];
      }
    }
    __syncthreads();
  }
}

// ---------------- setup: weight cast/permute + BN fold ----------------------
__global__ void k_setup(const float* __restrict__ Wq, const float* __restrict__ Wk,
                        const float* __restrict__ Wv, const float* __restrict__ Wm,
                        const float* __restrict__ W1, const float* __restrict__ W2,
                        const float* __restrict__ g, const float* __restrict__ be,
                        const float* __restrict__ mu, const float* __restrict__ va,
                        const float* __restrict__ b1, u16* __restrict__ wbf,
                        float* __restrict__ sc, float* __restrict__ sh) {
  int bid = blockIdx.x, tid = threadIdx.x;
  if (bid < 4608) {
    int which = bid / 1152, lb = bid - which * 1152;
    size_t i4 = ((size_t)lb * 256 + tid) * 4;
    int layer = (int)(i4 >> 16), rem = (int)(i4 & 65535);
    int row = rem >> 8, kk = rem & 255;
    const float* src = which == 0 ? Wq : which == 1 ? Wk : which == 2 ? Wv : Wm;
    f32x4 a = *(const f32x4*)(src + i4);
    u16* dl = wbf + (size_t)layer * 655360 + which * 65536;
    if (which < 3) {
      float s = (which == 0) ? 0.125f : 1.0f;
      int rp = ((row & 3) << 6) | (row >> 2);
      u32x2 pk;
      pk[0] = (u32)f2bf(a[0] * s) | ((u32)f2bf(a[1] * s) << 16);
      pk[1] = (u32)f2bf(a[2] * s) | ((u32)f2bf(a[3] * s) << 16);
      *(u32x2*)(dl + rp * 256 + kk) = pk;
    } else {
#pragma unroll
      for (int e = 0; e < 4; ++e) {
        int ci = kk + e, cp = ((ci & 3) << 6) | (ci >> 2);
        dl[row * 256 + cp] = f2bf(a[e]);
      }
    }
  } else if (bid < 9216) {
    int lb = bid - 4608;
    size_t i4 = ((size_t)lb * 256 + tid) * 4;
    int layer = (int)(i4 >> 18);
    size_t rem = i4 & 262143;
    f32x4 a = *(const f32x4*)(W1 + i4);
    u32x2 pk;
    pk[0] = (u32)f2bf(a[0]) | ((u32)f2bf(a[1]) << 16);
    pk[1] = (u32)f2bf(a[2]) | ((u32)f2bf(a[3]) << 16);
    *(u32x2*)(wbf + (size_t)layer * 655360 + 262144 + rem) = pk;
  } else if (bid < 11520) {
    int lb = bid - 9216;
    size_t i4 = ((size_t)lb * 256 + tid) * 4;
    int layer = (int)(i4 >> 17);
    size_t rem = i4 & 131071;
    f32x4 a = *(const f32x4*)(W2 + i4);
    u32x2 pk;
    pk[0] = (u32)f2bf(a[0]) | ((u32)f2bf(a[1]) << 16);
    pk[1] = (u32)f2bf(a[2]) | ((u32)f2bf(a[3]) << 16);
    *(u32x2*)(wbf + (size_t)layer * 655360 + 524288 + rem) = pk;
  } else {
    int i = (bid - 11520) * 256 + tid;
    if (i < 9216) {
      float s = g[i] * rsqrtf(va[i] + 1e-5f);
      sc[i] = s;
      sh[i] = s * (b1[i] - mu[i]) + be[i];
    }
  }
}

// ---------------- init ------------------------------------------------------
__global__ __launch_bounds__(256) void k_init(const float* __restrict__ d0,
                                              const float* __restrict__ d1,
                                              float* __restrict__ dstate,
                                              u16* __restrict__ y) {
  __shared__ float T[64 * 65];
  int b = blockIdx.z, cb = blockIdx.y * 64, nb = blockIdx.x * 64;
  int t = threadIdx.x, th = t >> 4, tl = t & 15;
  const float* src = (b < 2 ? d0 : d1) + (size_t)(b & 1) * 262144;
#pragma unroll
  for (int it = 0; it < 4; ++it) {
    int cl = it * 16 + th;
    f32x4 v = *(const f32x4*)(src + (size_t)(cb + cl) * 1024 + nb + tl * 4);
#pragma unroll
    for (int e = 0; e < 4; ++e) T[cl * 65 + tl * 4 + e] = v[e];
  }
  __syncthreads();
#pragma unroll
  for (int it = 0; it < 4; ++it) {
    int nl = it * 16 + th;
    f32x4 o;
#pragma unroll
    for (int e = 0; e < 4; ++e) o[e] = T[(tl * 4 + e) * 65 + nl];
    *(f32x4*)(dstate + (size_t)b * 262144 + (size_t)(nb + nl) * 256 + cb + tl * 4) = o;
    u32x2 pk;
    pk[0] = (u32)f2bf(o[0]) | ((u32)f2bf(o[1]) << 16);
    pk[1] = (u32)f2bf(o[2]) | ((u32)f2bf(o[3]) << 16);
    *(u32x2*)(y + (size_t)b * 524288 + (size_t)(nb + nl) * 512 + cb + tl * 4) = pk;
  }
}

// ---------------- layer-0 QKV ----------------------------------------------
__global__ __launch_bounds__(512) void k_qkv0(const u16* __restrict__ y,
                                              const u16* __restrict__ wln,
                                              const float* __restrict__ bqn,
                                              const float* __restrict__ bkn,
                                              const float* __restrict__ bvn,
                                              u16* __restrict__ qb, u16* __restrict__ kb,
                                              u16* __restrict__ vb) {
  const int row0 = blockIdx.x * 16, b = row0 >> 10, nb0 = row0 & 1023;
  const int tid = threadIdx.x, w = tid >> 6, lane = tid & 63;
  const int l4 = lane >> 4, l15 = lane & 15;
  const u16* Ar = y + (size_t)(row0 + l15) * 512 + l4 * 8;
  const u16* Br[6];
  f32x4 acc[6];
  int ty[6], cc[6];
#pragma unroll
  for (int s = 0; s < 6; ++s) {
    int gc = w * 96 + s * 16;
    ty[s] = gc >> 8;
    cc[s] = gc & 255;
    Br[s] = wln + ty[s] * 65536 + (size_t)(cc[s] + l15) * 256 + l4 * 8;
  }
  mm16g<6, 8>(Ar, Br, acc);
#pragma unroll
  for (int s = 0; s < 6; ++s) {
    int c = cc[s] + l15;
    int borig = ((c & 63) << 2) | (c >> 6);
    if (ty[s] == 0) {
      float bb = 0.125f * bqn[borig];
#pragma unroll
      for (int r = 0; r < 4; ++r)
        qb[(size_t)b * 262144 + (size_t)(nb0 + l4 * 4 + r) * 256 + c] = f2bf(acc[s][r] + bb);
    } else if (ty[s] == 1) {
      float bb = bkn[borig];
#pragma unroll
      for (int r = 0; r < 4; ++r)
        kb[(size_t)b * 262144 + (size_t)(nb0 + l4 * 4 + r) * 256 + c] = f2bf(acc[s][r] + bb);
    } else {
      float bb = bvn[borig];
      u32x2 pk;
      pk[0] = (u32)f2bf(acc[s][0] + bb) | ((u32)f2bf(acc[s][1] + bb) << 16);
      pk[1] = (u32)f2bf(acc[s][2] + bb) | ((u32)f2bf(acc[s][3] + bb) << 16);
      *(u32x2*)(vb + (size_t)b * 262144 + (size_t)c * 1024 + nb0 + l4 * 4) = pk;
    }
  }
}

// ---------------- flash attention, LDS-staged KV ----------------------------
// grid (16, 16): 64 q-rows x (b,h). 512 thr = 8 waves: qt=w&3, half=w>>2.
__global__ __launch_bounds__(512) void k_attn(const u16* __restrict__ qbuf,
                                              const u16* __restrict__ kbuf,
                                              const u16* __restrict__ vbuf,
                                              u16* __restrict__ att, int crossmask) {
  __shared__ char Kt[2][2][8192];  // [half][dbuf] 64 rows x 128B, XOR-swizzled
  __shared__ char Vt[2][2][8192];
  __shared__ char Ps[8][2304];
  __shared__ float Ms[4][16], Ls[4][16], Os[4][16][68];
  const int nb = blockIdx.x * 64;
  const int bh = blockIdx.y, b = bh >> 2, h = bh & 3;
  const int srcb = b ^ crossmask;
  const int tid = threadIdx.x, w = tid >> 6, lane = tid & 63;
  const int l4 = lane >> 4, l15 = lane & 15;
  const int qt = w & 3, half = w >> 2;
  char* P = Ps[w];
  const u16* Qb = qbuf + (size_t)b * 262144 + h * 64;
  const u16* Kb = kbuf + (size_t)srcb * 262144 + h * 64;
  const u16* Vb = vbuf + (size_t)srcb * 262144 + (size_t)h * 65536;
  // staging map: thread -> (row 0..63, 16B chunk 0..7) per tile
  const int srow = tid >> 3, sj = (tid & 7) * 16, sx = sj ^ ((srow & 7) << 4);
  const u16* gK[2] = {Kb, Kb + 512 * 256};
  const u16* gV[2] = {Vb, Vb + 512};

  const int qrow = nb + qt * 16;
  AB qf[2];
#pragma unroll
  for (int ks = 0; ks < 2; ++ks)
    qf[ks].q = *(const u32x4*)(Qb + (size_t)(qrow + l15) * 256 + ks * 32 + l4 * 8);

  u32x4 sk[2], sv[2];
#pragma unroll
  for (int H = 0; H < 2; ++H) {
    sk[H] = *(const u32x4*)((const char*)(gK[H] + (size_t)srow * 256) + sj);
    sv[H] = *(const u32x4*)((const char*)(gV[H] + (size_t)srow * 1024) + sj);
  }
#pragma unroll
  for (int H = 0; H < 2; ++H) {
    *(u32x4*)(Kt[H][0] + srow * 128 + sx) = sk[H];
    *(u32x4*)(Vt[H][0] + srow * 128 + sx) = sv[H];
  }
  __syncthreads();

  f32x4 oacc[4];
#pragma unroll
  for (int s = 0; s < 4; ++s) oacc[s] = (f32x4){0.f, 0.f, 0.f, 0.f};
  float mst = -1e30f, lst = 0.f;

#pragma unroll
  for (int mt = 0; mt < 8; ++mt) {
    const int cur = mt & 1, nx = cur ^ 1;
    if (mt < 7) {
#pragma unroll
      for (int H = 0; H < 2; ++H) {
        sk[H] = *(const u32x4*)((const char*)(gK[H] + (size_t)((mt + 1) * 64 + srow) * 256) + sj);
        sv[H] = *(const u32x4*)((const char*)(gV[H] + (size_t)srow * 1024 + (mt + 1) * 64) + sj);
      }
    }
    // S^T tile: A = K rows m, B = Q rows n ; lane: n=l15, m=sm*16+l4*4+r
    f32x4 sa[4];
#pragma unroll
    for (int sm = 0; sm < 4; ++sm) {
      sa[sm] = (f32x4){0.f, 0.f, 0.f, 0.f};
#pragma unroll
      for (int ks = 0; ks < 2; ++ks) {
        AB kf;
        int rr = sm * 16 + l15;
        kf.q = *(const u32x4*)(Kt[half][cur] + rr * 128 + ((ks * 64 + l4 * 16) ^ ((rr & 7) << 4)));
        sa[sm] = __builtin_amdgcn_mfma_f32_16x16x32_bf16(kf.s, qf[ks].s, sa[sm], 0, 0, 0);
      }
    }
    float m1 = fmaxf(fmaxf(fmaxf(sa[0][0], sa[0][1]), fmaxf(sa[0][2], sa[0][3])),
                     fmaxf(fmaxf(sa[1][0], sa[1][1]), fmaxf(sa[1][2], sa[1][3])));
    float m2 = fmaxf(fmaxf(fmaxf(sa[2][0], sa[2][1]), fmaxf(sa[2][2], sa[2][3])),
                     fmaxf(fmaxf(sa[3][0], sa[3][1]), fmaxf(sa[3][2], sa[3][3])));
    m1 = fmaxf(m1, m2);
    m1 = fmaxf(m1, __shfl_xor(m1, 16));
    m1 = fmaxf(m1, __shfl_xor(m1, 32));
    float mnew = fmaxf(mst, m1);
    float corr = __expf(mst - mnew);
    mst = mnew;
    float rs = 0.f;
#pragma unroll
    for (int sm = 0; sm < 4; ++sm)
#pragma unroll
      for (int r = 0; r < 4; ++r) {
        float p = __expf(sa[sm][r] - mnew);
        sa[sm][r] = p;
        rs += p;
      }
    rs += __shfl_xor(rs, 16);
    rs += __shfl_xor(rs, 32);
    lst = lst * corr + rs;
#pragma unroll
    for (int r = 0; r < 4; ++r) {
      float cr = __shfl(corr, l4 * 4 + r);
#pragma unroll
      for (int s = 0; s < 4; ++s) oacc[s][r] *= cr;
    }
#pragma unroll
    for (int sm = 0; sm < 4; ++sm) {
      u32x2 pk;
      pk[0] = (u32)f2bf(sa[sm][0]) | ((u32)f2bf(sa[sm][1]) << 16);
      pk[1] = (u32)f2bf(sa[sm][2]) | ((u32)f2bf(sa[sm][3]) << 16);
      *(u32x2*)(P + l15 * 136 + (sm * 16 + l4 * 4) * 2) = pk;
    }
#pragma unroll
    for (int ks = 0; ks < 2; ++ks) {
      AB pf;
      const char* ra = P + l15 * 136 + ks * 64 + l4 * 16;
      pf.d[0] = *(const u32x2*)ra;
      pf.d[1] = *(const u32x2*)(ra + 8);
#pragma unroll
      for (int s = 0; s < 4; ++s) {
        AB vf;
        int rr = s * 16 + l15;
        vf.q = *(const u32x4*)(Vt[half][cur] + rr * 128 + ((ks * 64 + l4 * 16) ^ ((rr & 7) << 4)));
        oacc[s] = __builtin_amdgcn_mfma_f32_16x16x32_bf16(pf.s, vf.s, oacc[s], 0, 0, 0);
      }
    }
    if (mt < 7) {
#pragma unroll
      for (int H = 0; H < 2; ++H) {
        *(u32x4*)(Kt[H][nx] + srow * 128 + sx) = sk[H];
        *(u32x4*)(Vt[H][nx] + srow * 128 + sx) = sv[H];
      }
    }
    __syncthreads();
  }
  if (half == 1) {
    Ms[qt][l15] = mst;
    Ls[qt][l15] = lst;
#pragma unroll
    for (int s = 0; s < 4; ++s)
#pragma unroll
      for (int r = 0; r < 4; ++r) Os[qt][l4 * 4 + r][s * 16 + l15] = oacc[s][r];
  }
  __syncthreads();
  if (half == 0) {
    float mb = Ms[qt][l15], lb = Ls[qt][l15];
    float M = fmaxf(mst, mb);
    float ea = __expf(mst - M), eb = __expf(mb - M);
    float rl = 1.f / (lst * ea + lb * eb);
    float fa = ea * rl, fb = eb * rl;
#pragma unroll
    for (int r = 0; r < 4; ++r) {
      float far = __shfl(fa, l4 * 4 + r);
      float fbr = __shfl(fb, l4 * 4 + r);
      int n = nb + qt * 16 + l4 * 4 + r;
#pragma unroll
      for (int s = 0; s < 4; ++s) {
        float ov = oacc[s][r] * far + Os[qt][l4 * 4 + r][s * 16 + l15] * fbr;
        att[(size_t)b * 262144 + (size_t)n * 256 + h * 64 + s * 16 + l15] = f2bf(ov);
      }
    }
  }
}

// ---------------- fused post: merge + mlp + residual + next QKV -------------
__global__ __launch_bounds__(1024) void k_post(
    const u16* __restrict__ att, const u16* __restrict__ wl, const u16* __restrict__ wln,
    const float* __restrict__ bm, const float* __restrict__ sc, const float* __restrict__ sh,
    const float* __restrict__ b2, const float* __restrict__ bqn,
    const float* __restrict__ bkn, const float* __restrict__ bvn,
    float* __restrict__ dstate, u16* __restrict__ y, u16* __restrict__ qb,
    u16* __restrict__ kb, u16* __restrict__ vb, float* __restrict__ out, int cross, int j,
    int last) {
  __shared__ char yT[16384];  // [16][512ch] bf16, 16B-XOR swizzled
  __shared__ char hT[16384];
  __shared__ char Wb[98304];  // weight slab double-buffer
  const int row0 = blockIdx.x * 16, b = row0 >> 10, nb0 = row0 & 1023;
  const int tid = threadIdx.x, w = tid >> 6, lane = tid & 63;
  const int l4 = lane >> 4, l15 = lane & 15;

  {  // stage yT (x-half fresh; msg half overwritten by stage1)
    int rr = tid >> 6, ch = tid & 63;
    u32x4 v = *(const u32x4*)(y + (size_t)(row0 + rr) * 512 + ch * 8);
    *(u32x4*)(yT + ((rr * 1024 + ch * 16) ^ ((rr & 7) << 4))) = v;
  }
  {  // stage1: msg = att @ Wm^T + bm -> yT[.,256:512]
    f32x4 acc[1];
    const u16* Ag = att + (size_t)(row0 + l15) * 256 + l4 * 8;
    stageW<256, 256, 1, false>(wl + 196608, Wb, nullptr, Ag, acc, tid, w, l4, l15);
    int c = w * 16 + l15;
    float bb = bm[c];
#pragma unroll
    for (int r = 0; r < 4; ++r) {
      int rw = l4 * 4 + r;
      *(u16*)(yT + ((rw * 1024 + (256 + c) * 2) ^ ((rw & 7) << 4))) = f2bf(acc[0][r] + bb);
    }
  }
  {  // stage2: h = relu(sc*(W1 y)+sh) -> hT
    f32x4 acc[2];
    stageW<512, 512, 2, true>(wl + 262144, Wb, yT, nullptr, acc, tid, w, l4, l15);
#pragma unroll
    for (int s = 0; s < 2; ++s) {
      int c = w * 32 + s * 16 + l15;
      float s_ = sc[c], t_ = sh[c];
#pragma unroll
      for (int r = 0; r < 4; ++r) {
        int rw = l4 * 4 + r;
        *(u16*)(hT + ((rw * 1024 + c * 2) ^ ((rw & 7) << 4))) =
            f2bf(fmaxf(s_ * acc[s][r] + t_, 0.f));
      }
    }
  }
  {  // stage3: delta = W2 h + b2 ; residual ; y ; out
    f32x4 acc[1];
    stageW<256, 512, 1, true>(wl + 524288, Wb, hT, nullptr, acc, tid, w, l4, l15);
    float* ob = out + (size_t)(((b >> 1) * 9 + j) * 2 + (b & 1)) * 262144;
    int c = w * 16 + l15;
    float bb = b2[c];
#pragma unroll
    for (int r = 0; r < 4; ++r) {
      int rw = l4 * 4 + r;
      size_t di = (size_t)(row0 + rw) * 256 + c;
      float nv = dstate[di] + acc[0][r] + bb;
      dstate[di] = nv;
      u16 bv16 = f2bf(nv);
      y[(size_t)(row0 + rw) * 512 + c] = bv16;
      *(u16*)(yT + ((rw * 1024 + c * 2) ^ ((rw & 7) << 4))) = bv16;
      if (cross) ob[(size_t)c * 1024 + nb0 + rw] = nv;
    }
  }
  if (last) return;
  {  // stage4: next-layer QKV (768 cols over Q|K|V), x-half of yT (k<256)
    f32x4 acc[3];
    stageW<768, 256, 3, true>(wln, Wb, yT, nullptr, acc, tid, w, l4, l15);
#pragma unroll
    for (int s = 0; s < 3; ++s) {
      int gc = w * 48 + s * 16;
      int ty = gc >> 8;
      int c = (gc & 255) + l15;
      int borig = ((c & 63) << 2) | (c >> 6);
      if (ty == 0) {
        float bb = 0.125f * bqn[borig];
#pragma unroll
        for (int r = 0; r < 4; ++r)
          qb[(size_t)b * 262144 + (size_t)(nb0 + l4 * 4 + r) * 256 + c] = f2bf(acc[s][r] + bb);
      } else if (ty == 1) {
        float bb = bkn[borig];
#pragma unroll
        for (int r = 0; r < 4; ++r)
          kb[(size_t)b * 262144 + (size_t)(nb0 + l4 * 4 + r) * 256 + c] = f2bf(acc[s][r] + bb);
      } else {
        float bb = bvn[borig];
        u32x2 pk;
        pk[0] = (u32)f2bf(acc[s][0] + bb) | ((u32)f2bf(acc[s][1] + bb) << 16);
        pk[1] = (u32)f2bf(acc[s][2] + bb) | ((u32)f2bf(acc[s][3] + bb) << 16);
        *(u32x2*)(vb + (size_t)b * 262144 + (size_t)c * 1024 + nb0 + l4 * 4) = pk;
      }
    }
  }
}

// ---------------- host ------------------------------------------------------
extern "C" void kernel_launch(void* const* d_in, const int* in_sizes, int n_in,
                              void* d_out, int out_size, void* d_ws, size_t ws_size,
                              hipStream_t stream) {
  const float* desc0 = (const float*)d_in[0];
  const float* desc1 = (const float*)d_in[1];
  const float* Wq = (const float*)d_in[2];
  const float* bq = (const float*)d_in[3];
  const float* Wk = (const float*)d_in[4];
  const float* bk = (const float*)d_in[5];
  const float* Wv = (const float*)d_in[6];
  const float* bv = (const float*)d_in[7];
  const float* Wm = (const float*)d_in[8];
  const float* bm = (const float*)d_in[9];
  const float* W1 = (const float*)d_in[10];
  const float* b1 = (const float*)d_in[11];
  const float* gamma = (const float*)d_in[12];
  const float* beta = (const float*)d_in[13];
  const float* mu = (const float*)d_in[14];
  const float* var = (const float*)d_in[15];
  const float* W2 = (const float*)d_in[16];
  const float* b2 = (const float*)d_in[17];

  char* ws = (char*)d_ws;
  float* dstate = (float*)ws;                   // 4 MB
  u16* y = (u16*)(ws + ((size_t)4 << 20));      // 4 MB
  u16* qb = (u16*)(ws + ((size_t)8 << 20));     // 2 MB
  u16* kb = (u16*)(ws + ((size_t)10 << 20));    // 2 MB
  u16* vb = (u16*)(ws + ((size_t)12 << 20));    // 2 MB
  u16* attb = (u16*)(ws + ((size_t)14 << 20));  // 2 MB
  u16* wbf = (u16*)(ws + ((size_t)16 << 20));   // 23.6 MB
  float* scb = (float*)(ws + ((size_t)40 << 20));
  float* shb = (float*)(ws + ((size_t)41 << 20));

  k_setup<<<11556, 256, 0, stream>>>(Wq, Wk, Wv, Wm, W1, W2, gamma, beta, mu, var, b1,
                                     wbf, scb, shb);
  k_init<<<dim3(16, 4, 4), 256, 0, stream>>>(desc0, desc1, dstate, y);
  k_qkv0<<<256, 512, 0, stream>>>(y, wbf, bq, bk, bv, qb, kb, vb);

  for (int i = 0; i < 18; ++i) {
    int cross = i & 1;
    const u16* wl = wbf + (size_t)i * 655360;
    int nl = (i < 17) ? i + 1 : 0;
    const u16* wln = wbf + (size_t)nl * 655360;
    k_attn<<<dim3(16, 16), 512, 0, stream>>>(qb, kb, vb, attb, cross ? 2 : 0);
    k_post<<<256, 1024, 0, stream>>>(attb, wl, wln, bm + i * 256, scb + (size_t)i * 512,
                                     shb + (size_t)i * 512, b2 + i * 256, bq + nl * 256,
                                     bk + nl * 256, bv + nl * 256, dstate, y, qb, kb, vb,
                                     (float*)d_out, cross, i >> 1, i == 17);
  }
}

// Round 6
// 830.027 us; speedup vs baseline: 2.7071x; 1.1511x over previous
//
#include <hip/hip_runtime.h>
#include <math.h>

// GraphMatcher R6: R5 + counted-wait pipeline in k_post's weight streaming.
//  stageW2: 2-deep slab prefetch; raw s_barrier + lgkmcnt(0) (no vmem drain),
//  so slab+2 global loads stay in flight across barriers (T4).
// Everything else identical to the passing R5 build.

typedef unsigned short u16;
typedef unsigned int u32;
typedef __attribute__((ext_vector_type(4))) unsigned int u32x4;
typedef __attribute__((ext_vector_type(2))) unsigned int u32x2;
typedef __attribute__((ext_vector_type(8))) short short8v;
typedef __attribute__((ext_vector_type(4))) float f32x4;

union AB { u32x4 q; u32x2 d[2]; short8v s; };

__device__ __forceinline__ u16 f2bf(float f) {
  u32 u = __builtin_bit_cast(u32, f);
  u32 r = u + 0x7fffu + ((u >> 16) & 1u);
  return (u16)(r >> 16);
}

#define LBAR()                                           \
  do {                                                   \
    asm volatile("s_waitcnt lgkmcnt(0)" ::: "memory");   \
    __builtin_amdgcn_s_barrier();                        \
    asm volatile("" ::: "memory");                       \
  } while (0)

// ---- M=16 GEMM, A rows l15-indexed k-contig from global (k_qkv0 only) ----
template<int SN, int NK>
__device__ __forceinline__ void mm16g(const u16* __restrict__ Ar,
                                      const u16* const (&Br)[SN], f32x4 (&acc)[SN]) {
#pragma unroll
  for (int s = 0; s < SN; ++s) acc[s] = (f32x4){0.f, 0.f, 0.f, 0.f};
  AB a[2], b[2][SN];
  a[0].q = *(const u32x4*)(Ar);
#pragma unroll
  for (int s = 0; s < SN; ++s) b[0][s].q = *(const u32x4*)(Br[s]);
#pragma unroll
  for (int kp = 0; kp < NK; ++kp) {
    const int cu = kp & 1, nx = cu ^ 1;
    if (kp + 1 < NK) {
      a[nx].q = *(const u32x4*)(Ar + (kp + 1) * 32);
#pragma unroll
      for (int s = 0; s < SN; ++s) b[nx][s].q = *(const u32x4*)(Br[s] + (kp + 1) * 32);
    }
#pragma unroll
    for (int s = 0; s < SN; ++s)
      acc[s] = __builtin_amdgcn_mfma_f32_16x16x32_bf16(a[cu].s, b[cu][s].s, acc[s], 0, 0, 0);
  }
}

// ---- k_post core v2: C[16][N] = A[16][Kd] * W[N][Kd]^T -------------------
// 1024 thr. W streamed thru LDS dbuf with 2-deep prefetch + counted waits.
template<int N, int Kd, int SN, bool ALDS>
__device__ __forceinline__ void stageW2(const u16* __restrict__ W, char* __restrict__ Wb,
                                        const char* __restrict__ Alds,
                                        const u16* __restrict__ Ag, f32x4 (&acc)[SN],
                                        int tid, int w, int l4, int l15) {
  constexpr int NS = Kd / 32;
  constexpr int CH = (N * 4) / 1024;  // 16B chunks per thread per slab
  const int colb = tid >> 2, jb = (tid & 3) * 16;
  u32x4 st0[CH], st1[CH];  // static parity sets (rule #20)
  // prologue: issue slabs 0,1 ; write slab0 ; barrier
#pragma unroll
  for (int c = 0; c < CH; ++c)
    st0[c] = *(const u32x4*)((const char*)(W + (size_t)(colb + c * 256) * Kd) + jb);
#pragma unroll
  for (int c = 0; c < CH; ++c)
    st1[c] = *(const u32x4*)((const char*)(W + (size_t)(colb + c * 256) * Kd + 32) + jb);
#pragma unroll
  for (int c = 0; c < CH; ++c) {
    int col = colb + c * 256;
    *(u32x4*)(Wb + col * 64 + (jb ^ ((col & 3) << 4))) = st0[c];
  }
#pragma unroll
  for (int s = 0; s < SN; ++s) acc[s] = (f32x4){0.f, 0.f, 0.f, 0.f};
  LBAR();
#pragma unroll
  for (int slab = 0; slab < NS; ++slab) {
    const int cur = slab & 1;
    if (slab + 2 < NS) {  // issue slab+2 into set parity (slab&1)
#pragma unroll
      for (int c = 0; c < CH; ++c) {
        const char* src =
            (const char*)(W + (size_t)(colb + c * 256) * Kd + (slab + 2) * 32) + jb;
        if (cur == 0) st0[c] = *(const u32x4*)src;
        else st1[c] = *(const u32x4*)src;
      }
    }
    AB af;
    if constexpr (ALDS) {
      int ab = l15 * 1024 + slab * 64 + l4 * 16;
      af.q = *(const u32x4*)(Alds + (ab ^ ((l15 & 7) << 4)));
    } else {
      af.q = *(const u32x4*)(Ag + slab * 32);
    }
    const char* rb = Wb + cur * (N * 64);
#pragma unroll
    for (int s = 0; s < SN; ++s) {
      int col = w * (16 * SN) + s * 16 + l15;
      AB bf;
      bf.q = *(const u32x4*)(rb + col * 64 + ((l4 * 16) ^ ((col & 3) << 4)));
      acc[s] = __builtin_amdgcn_mfma_f32_16x16x32_bf16(af.s, bf.s, acc[s], 0, 0, 0);
    }
    if (slab + 1 < NS) {  // write slab+1 (set parity (slab+1)&1) to other buf
      char* wb2 = Wb + (cur ^ 1) * (N * 64);
#pragma unroll
      for (int c = 0; c < CH; ++c) {
        int col = colb + c * 256;
        u32x4 v;
        if (cur == 0) v = st1[c];
        else v = st0[c];
        *(u32x4*)(wb2 + col * 64 + (jb ^ ((col & 3) << 4))) = v;
      }
    }
    LBAR();
  }
}

// ---------------- setup: weight cast/permute + BN fold ----------------------
__global__ void k_setup(const float* __restrict__ Wq, const float* __restrict__ Wk,
                        const float* __restrict__ Wv, const float* __restrict__ Wm,
                        const float* __restrict__ W1, const float* __restrict__ W2,
                        const float* __restrict__ g, const float* __restrict__ be,
                        const float* __restrict__ mu, const float* __restrict__ va,
                        const float* __restrict__ b1, u16* __restrict__ wbf,
                        float* __restrict__ sc, float* __restrict__ sh) {
  int bid = blockIdx.x, tid = threadIdx.x;
  if (bid < 4608) {
    int which = bid / 1152, lb = bid - which * 1152;
    size_t i4 = ((size_t)lb * 256 + tid) * 4;
    int layer = (int)(i4 >> 16), rem = (int)(i4 & 65535);
    int row = rem >> 8, kk = rem & 255;
    const float* src = which == 0 ? Wq : which == 1 ? Wk : which == 2 ? Wv : Wm;
    f32x4 a = *(const f32x4*)(src + i4);
    u16* dl = wbf + (size_t)layer * 655360 + which * 65536;
    if (which < 3) {
      float s = (which == 0) ? 0.125f : 1.0f;
      int rp = ((row & 3) << 6) | (row >> 2);
      u32x2 pk;
      pk[0] = (u32)f2bf(a[0] * s) | ((u32)f2bf(a[1] * s) << 16);
      pk[1] = (u32)f2bf(a[2] * s) | ((u32)f2bf(a[3] * s) << 16);
      *(u32x2*)(dl + rp * 256 + kk) = pk;
    } else {
#pragma unroll
      for (int e = 0; e < 4; ++e) {
        int ci = kk + e, cp = ((ci & 3) << 6) | (ci >> 2);
        dl[row * 256 + cp] = f2bf(a[e]);
      }
    }
  } else if (bid < 9216) {
    int lb = bid - 4608;
    size_t i4 = ((size_t)lb * 256 + tid) * 4;
    int layer = (int)(i4 >> 18);
    size_t rem = i4 & 262143;
    f32x4 a = *(const f32x4*)(W1 + i4);
    u32x2 pk;
    pk[0] = (u32)f2bf(a[0]) | ((u32)f2bf(a[1]) << 16);
    pk[1] = (u32)f2bf(a[2]) | ((u32)f2bf(a[3]) << 16);
    *(u32x2*)(wbf + (size_t)layer * 655360 + 262144 + rem) = pk;
  } else if (bid < 11520) {
    int lb = bid - 9216;
    size_t i4 = ((size_t)lb * 256 + tid) * 4;
    int layer = (int)(i4 >> 17);
    size_t rem = i4 & 131071;
    f32x4 a = *(const f32x4*)(W2 + i4);
    u32x2 pk;
    pk[0] = (u32)f2bf(a[0]) | ((u32)f2bf(a[1]) << 16);
    pk[1] = (u32)f2bf(a[2]) | ((u32)f2bf(a[3]) << 16);
    *(u32x2*)(wbf + (size_t)layer * 655360 + 524288 + rem) = pk;
  } else {
    int i = (bid - 11520) * 256 + tid;
    if (i < 9216) {
      float s = g[i] * rsqrtf(va[i] + 1e-5f);
      sc[i] = s;
      sh[i] = s * (b1[i] - mu[i]) + be[i];
    }
  }
}

// ---------------- init ------------------------------------------------------
__global__ __launch_bounds__(256) void k_init(const float* __restrict__ d0,
                                              const float* __restrict__ d1,
                                              float* __restrict__ dstate,
                                              u16* __restrict__ y) {
  __shared__ float T[64 * 65];
  int b = blockIdx.z, cb = blockIdx.y * 64, nb = blockIdx.x * 64;
  int t = threadIdx.x, th = t >> 4, tl = t & 15;
  const float* src = (b < 2 ? d0 : d1) + (size_t)(b & 1) * 262144;
#pragma unroll
  for (int it = 0; it < 4; ++it) {
    int cl = it * 16 + th;
    f32x4 v = *(const f32x4*)(src + (size_t)(cb + cl) * 1024 + nb + tl * 4);
#pragma unroll
    for (int e = 0; e < 4; ++e) T[cl * 65 + tl * 4 + e] = v[e];
  }
  __syncthreads();
#pragma unroll
  for (int it = 0; it < 4; ++it) {
    int nl = it * 16 + th;
    f32x4 o;
#pragma unroll
    for (int e = 0; e < 4; ++e) o[e] = T[(tl * 4 + e) * 65 + nl];
    *(f32x4*)(dstate + (size_t)b * 262144 + (size_t)(nb + nl) * 256 + cb + tl * 4) = o;
    u32x2 pk;
    pk[0] = (u32)f2bf(o[0]) | ((u32)f2bf(o[1]) << 16);
    pk[1] = (u32)f2bf(o[2]) | ((u32)f2bf(o[3]) << 16);
    *(u32x2*)(y + (size_t)b * 524288 + (size_t)(nb + nl) * 512 + cb + tl * 4) = pk;
  }
}

// ---------------- layer-0 QKV ----------------------------------------------
__global__ __launch_bounds__(512) void k_qkv0(const u16* __restrict__ y,
                                              const u16* __restrict__ wln,
                                              const float* __restrict__ bqn,
                                              const float* __restrict__ bkn,
                                              const float* __restrict__ bvn,
                                              u16* __restrict__ qb, u16* __restrict__ kb,
                                              u16* __restrict__ vb) {
  const int row0 = blockIdx.x * 16, b = row0 >> 10, nb0 = row0 & 1023;
  const int tid = threadIdx.x, w = tid >> 6, lane = tid & 63;
  const int l4 = lane >> 4, l15 = lane & 15;
  const u16* Ar = y + (size_t)(row0 + l15) * 512 + l4 * 8;
  const u16* Br[6];
  f32x4 acc[6];
  int ty[6], cc[6];
#pragma unroll
  for (int s = 0; s < 6; ++s) {
    int gc = w * 96 + s * 16;
    ty[s] = gc >> 8;
    cc[s] = gc & 255;
    Br[s] = wln + ty[s] * 65536 + (size_t)(cc[s] + l15) * 256 + l4 * 8;
  }
  mm16g<6, 8>(Ar, Br, acc);
#pragma unroll
  for (int s = 0; s < 6; ++s) {
    int c = cc[s] + l15;
    int borig = ((c & 63) << 2) | (c >> 6);
    if (ty[s] == 0) {
      float bb = 0.125f * bqn[borig];
#pragma unroll
      for (int r = 0; r < 4; ++r)
        qb[(size_t)b * 262144 + (size_t)(nb0 + l4 * 4 + r) * 256 + c] = f2bf(acc[s][r] + bb);
    } else if (ty[s] == 1) {
      float bb = bkn[borig];
#pragma unroll
      for (int r = 0; r < 4; ++r)
        kb[(size_t)b * 262144 + (size_t)(nb0 + l4 * 4 + r) * 256 + c] = f2bf(acc[s][r] + bb);
    } else {
      float bb = bvn[borig];
      u32x2 pk;
      pk[0] = (u32)f2bf(acc[s][0] + bb) | ((u32)f2bf(acc[s][1] + bb) << 16);
      pk[1] = (u32)f2bf(acc[s][2] + bb) | ((u32)f2bf(acc[s][3] + bb) << 16);
      *(u32x2*)(vb + (size_t)b * 262144 + (size_t)c * 1024 + nb0 + l4 * 4) = pk;
    }
  }
}

// ---------------- flash attention, LDS-staged KV ----------------------------
__global__ __launch_bounds__(512) void k_attn(const u16* __restrict__ qbuf,
                                              const u16* __restrict__ kbuf,
                                              const u16* __restrict__ vbuf,
                                              u16* __restrict__ att, int crossmask) {
  __shared__ char Kt[2][2][8192];
  __shared__ char Vt[2][2][8192];
  __shared__ char Ps[8][2304];
  __shared__ float Ms[4][16], Ls[4][16], Os[4][16][68];
  const int nb = blockIdx.x * 64;
  const int bh = blockIdx.y, b = bh >> 2, h = bh & 3;
  const int srcb = b ^ crossmask;
  const int tid = threadIdx.x, w = tid >> 6, lane = tid & 63;
  const int l4 = lane >> 4, l15 = lane & 15;
  const int qt = w & 3, half = w >> 2;
  char* P = Ps[w];
  const u16* Qb = qbuf + (size_t)b * 262144 + h * 64;
  const u16* Kb = kbuf + (size_t)srcb * 262144 + h * 64;
  const u16* Vb = vbuf + (size_t)srcb * 262144 + (size_t)h * 65536;
  const int srow = tid >> 3, sj = (tid & 7) * 16, sx = sj ^ ((srow & 7) << 4);
  const u16* gK[2] = {Kb, Kb + 512 * 256};
  const u16* gV[2] = {Vb, Vb + 512};

  const int qrow = nb + qt * 16;
  AB qf[2];
#pragma unroll
  for (int ks = 0; ks < 2; ++ks)
    qf[ks].q = *(const u32x4*)(Qb + (size_t)(qrow + l15) * 256 + ks * 32 + l4 * 8);

  u32x4 sk[2], sv[2];
#pragma unroll
  for (int H = 0; H < 2; ++H) {
    sk[H] = *(const u32x4*)((const char*)(gK[H] + (size_t)srow * 256) + sj);
    sv[H] = *(const u32x4*)((const char*)(gV[H] + (size_t)srow * 1024) + sj);
  }
#pragma unroll
  for (int H = 0; H < 2; ++H) {
    *(u32x4*)(Kt[H][0] + srow * 128 + sx) = sk[H];
    *(u32x4*)(Vt[H][0] + srow * 128 + sx) = sv[H];
  }
  __syncthreads();

  f32x4 oacc[4];
#pragma unroll
  for (int s = 0; s < 4; ++s) oacc[s] = (f32x4){0.f, 0.f, 0.f, 0.f};
  float mst = -1e30f, lst = 0.f;

#pragma unroll
  for (int mt = 0; mt < 8; ++mt) {
    const int cur = mt & 1, nx = cur ^ 1;
    if (mt < 7) {
#pragma unroll
      for (int H = 0; H < 2; ++H) {
        sk[H] = *(const u32x4*)((const char*)(gK[H] + (size_t)((mt + 1) * 64 + srow) * 256) + sj);
        sv[H] = *(const u32x4*)((const char*)(gV[H] + (size_t)srow * 1024 + (mt + 1) * 64) + sj);
      }
    }
    f32x4 sa[4];
#pragma unroll
    for (int sm = 0; sm < 4; ++sm) {
      sa[sm] = (f32x4){0.f, 0.f, 0.f, 0.f};
#pragma unroll
      for (int ks = 0; ks < 2; ++ks) {
        AB kf;
        int rr = sm * 16 + l15;
        kf.q = *(const u32x4*)(Kt[half][cur] + rr * 128 + ((ks * 64 + l4 * 16) ^ ((rr & 7) << 4)));
        sa[sm] = __builtin_amdgcn_mfma_f32_16x16x32_bf16(kf.s, qf[ks].s, sa[sm], 0, 0, 0);
      }
    }
    float m1 = fmaxf(fmaxf(fmaxf(sa[0][0], sa[0][1]), fmaxf(sa[0][2], sa[0][3])),
                     fmaxf(fmaxf(sa[1][0], sa[1][1]), fmaxf(sa[1][2], sa[1][3])));
    float m2 = fmaxf(fmaxf(fmaxf(sa[2][0], sa[2][1]), fmaxf(sa[2][2], sa[2][3])),
                     fmaxf(fmaxf(sa[3][0], sa[3][1]), fmaxf(sa[3][2], sa[3][3])));
    m1 = fmaxf(m1, m2);
    m1 = fmaxf(m1, __shfl_xor(m1, 16));
    m1 = fmaxf(m1, __shfl_xor(m1, 32));
    float mnew = fmaxf(mst, m1);
    float corr = __expf(mst - mnew);
    mst = mnew;
    float rs = 0.f;
#pragma unroll
    for (int sm = 0; sm < 4; ++sm)
#pragma unroll
      for (int r = 0; r < 4; ++r) {
        float p = __expf(sa[sm][r] - mnew);
        sa[sm][r] = p;
        rs += p;
      }
    rs += __shfl_xor(rs, 16);
    rs += __shfl_xor(rs, 32);
    lst = lst * corr + rs;
#pragma unroll
    for (int r = 0; r < 4; ++r) {
      float cr = __shfl(corr, l4 * 4 + r);
#pragma unroll
      for (int s = 0; s < 4; ++s) oacc[s][r] *= cr;
    }
#pragma unroll
    for (int sm = 0; sm < 4; ++sm) {
      u32x2 pk;
      pk[0] = (u32)f2bf(sa[sm][0]) | ((u32)f2bf(sa[sm][1]) << 16);
      pk[1] = (u32)f2bf(sa[sm][2]) | ((u32)f2bf(sa[sm][3]) << 16);
      *(u32x2*)(P + l15 * 136 + (sm * 16 + l4 * 4) * 2) = pk;
    }
#pragma unroll
    for (int ks = 0; ks < 2; ++ks) {
      AB pf;
      const char* ra = P + l15 * 136 + ks * 64 + l4 * 16;
      pf.d[0] = *(const u32x2*)ra;
      pf.d[1] = *(const u32x2*)(ra + 8);
#pragma unroll
      for (int s = 0; s < 4; ++s) {
        AB vf;
        int rr = s * 16 + l15;
        vf.q = *(const u32x4*)(Vt[half][cur] + rr * 128 + ((ks * 64 + l4 * 16) ^ ((rr & 7) << 4)));
        oacc[s] = __builtin_amdgcn_mfma_f32_16x16x32_bf16(pf.s, vf.s, oacc[s], 0, 0, 0);
      }
    }
    if (mt < 7) {
#pragma unroll
      for (int H = 0; H < 2; ++H) {
        *(u32x4*)(Kt[H][nx] + srow * 128 + sx) = sk[H];
        *(u32x4*)(Vt[H][nx] + srow * 128 + sx) = sv[H];
      }
    }
    __syncthreads();
  }
  if (half == 1) {
    Ms[qt][l15] = mst;
    Ls[qt][l15] = lst;
#pragma unroll
    for (int s = 0; s < 4; ++s)
#pragma unroll
      for (int r = 0; r < 4; ++r) Os[qt][l4 * 4 + r][s * 16 + l15] = oacc[s][r];
  }
  __syncthreads();
  if (half == 0) {
    float mb = Ms[qt][l15], lb = Ls[qt][l15];
    float M = fmaxf(mst, mb);
    float ea = __expf(mst - M), eb = __expf(mb - M);
    float rl = 1.f / (lst * ea + lb * eb);
    float fa = ea * rl, fb = eb * rl;
#pragma unroll
    for (int r = 0; r < 4; ++r) {
      float far = __shfl(fa, l4 * 4 + r);
      float fbr = __shfl(fb, l4 * 4 + r);
      int n = nb + qt * 16 + l4 * 4 + r;
#pragma unroll
      for (int s = 0; s < 4; ++s) {
        float ov = oacc[s][r] * far + Os[qt][l4 * 4 + r][s * 16 + l15] * fbr;
        att[(size_t)b * 262144 + (size_t)n * 256 + h * 64 + s * 16 + l15] = f2bf(ov);
      }
    }
  }
}

// ---------------- fused post: merge + mlp + residual + next QKV -------------
__global__ __launch_bounds__(1024) void k_post(
    const u16* __restrict__ att, const u16* __restrict__ wl, const u16* __restrict__ wln,
    const float* __restrict__ bm, const float* __restrict__ sc, const float* __restrict__ sh,
    const float* __restrict__ b2, const float* __restrict__ bqn,
    const float* __restrict__ bkn, const float* __restrict__ bvn,
    float* __restrict__ dstate, u16* __restrict__ y, u16* __restrict__ qb,
    u16* __restrict__ kb, u16* __restrict__ vb, float* __restrict__ out, int cross, int j,
    int last) {
  __shared__ char yT[16384];  // [16][512ch] bf16, 16B-XOR swizzled
  __shared__ char hT[16384];
  __shared__ char Wb[98304];  // weight slab double-buffer
  const int row0 = blockIdx.x * 16, b = row0 >> 10, nb0 = row0 & 1023;
  const int tid = threadIdx.x, w = tid >> 6, lane = tid & 63;
  const int l4 = lane >> 4, l15 = lane & 15;

  {  // stage yT (x-half fresh; msg half overwritten by stage1)
    int rr = tid >> 6, ch = tid & 63;
    u32x4 v = *(const u32x4*)(y + (size_t)(row0 + rr) * 512 + ch * 8);
    *(u32x4*)(yT + ((rr * 1024 + ch * 16) ^ ((rr & 7) << 4))) = v;
  }
  {  // stage1: msg = att @ Wm^T + bm -> yT[.,256:512]
    f32x4 acc[1];
    const u16* Ag = att + (size_t)(row0 + l15) * 256 + l4 * 8;
    stageW2<256, 256, 1, false>(wl + 196608, Wb, nullptr, Ag, acc, tid, w, l4, l15);
    int c = w * 16 + l15;
    float bb = bm[c];
#pragma unroll
    for (int r = 0; r < 4; ++r) {
      int rw = l4 * 4 + r;
      *(u16*)(yT + ((rw * 1024 + (256 + c) * 2) ^ ((rw & 7) << 4))) = f2bf(acc[0][r] + bb);
    }
  }
  {  // stage2: h = relu(sc*(W1 y)+sh) -> hT
    f32x4 acc[2];
    stageW2<512, 512, 2, true>(wl + 262144, Wb, yT, nullptr, acc, tid, w, l4, l15);
#pragma unroll
    for (int s = 0; s < 2; ++s) {
      int c = w * 32 + s * 16 + l15;
      float s_ = sc[c], t_ = sh[c];
#pragma unroll
      for (int r = 0; r < 4; ++r) {
        int rw = l4 * 4 + r;
        *(u16*)(hT + ((rw * 1024 + c * 2) ^ ((rw & 7) << 4))) =
            f2bf(fmaxf(s_ * acc[s][r] + t_, 0.f));
      }
    }
  }
  {  // stage3: delta = W2 h + b2 ; residual ; y ; out
    f32x4 acc[1];
    stageW2<256, 512, 1, true>(wl + 524288, Wb, hT, nullptr, acc, tid, w, l4, l15);
    float* ob = out + (size_t)(((b >> 1) * 9 + j) * 2 + (b & 1)) * 262144;
    int c = w * 16 + l15;
    float bb = b2[c];
#pragma unroll
    for (int r = 0; r < 4; ++r) {
      int rw = l4 * 4 + r;
      size_t di = (size_t)(row0 + rw) * 256 + c;
      float nv = dstate[di] + acc[0][r] + bb;
      dstate[di] = nv;
      u16 bv16 = f2bf(nv);
      y[(size_t)(row0 + rw) * 512 + c] = bv16;
      *(u16*)(yT + ((rw * 1024 + c * 2) ^ ((rw & 7) << 4))) = bv16;
      if (cross) ob[(size_t)c * 1024 + nb0 + rw] = nv;
    }
  }
  if (last) return;
  {  // stage4: next-layer QKV (768 cols over Q|K|V), x-half of yT (k<256)
    f32x4 acc[3];
    stageW2<768, 256, 3, true>(wln, Wb, yT, nullptr, acc, tid, w, l4, l15);
#pragma unroll
    for (int s = 0; s < 3; ++s) {
      int gc = w * 48 + s * 16;
      int ty = gc >> 8;
      int c = (gc & 255) + l15;
      int borig = ((c & 63) << 2) | (c >> 6);
      if (ty == 0) {
        float bb = 0.125f * bqn[borig];
#pragma unroll
        for (int r = 0; r < 4; ++r)
          qb[(size_t)b * 262144 + (size_t)(nb0 + l4 * 4 + r) * 256 + c] = f2bf(acc[s][r] + bb);
      } else if (ty == 1) {
        float bb = bkn[borig];
#pragma unroll
        for (int r = 0; r < 4; ++r)
          kb[(size_t)b * 262144 + (size_t)(nb0 + l4 * 4 + r) * 256 + c] = f2bf(acc[s][r] + bb);
      } else {
        float bb = bvn[borig];
        u32x2 pk;
        pk[0] = (u32)f2bf(acc[s][0] + bb) | ((u32)f2bf(acc[s][1] + bb) << 16);
        pk[1] = (u32)f2bf(acc[s][2] + bb) | ((u32)f2bf(acc[s][3] + bb) << 16);
        *(u32x2*)(vb + (size_t)b * 262144 + (size_t)c * 1024 + nb0 + l4 * 4) = pk;
      }
    }
  }
}

// ---------------- host ------------------------------------------------------
extern "C" void kernel_launch(void* const* d_in, const int* in_sizes, int n_in,
                              void* d_out, int out_size, void* d_ws, size_t ws_size,
                              hipStream_t stream) {
  const float* desc0 = (const float*)d_in[0];
  const float* desc1 = (const float*)d_in[1];
  const float* Wq = (const float*)d_in[2];
  const float* bq = (const float*)d_in[3];
  const float* Wk = (const float*)d_in[4];
  const float* bk = (const float*)d_in[5];
  const float* Wv = (const float*)d_in[6];
  const float* bv = (const float*)d_in[7];
  const float* Wm = (const float*)d_in[8];
  const float* bm = (const float*)d_in[9];
  const float* W1 = (const float*)d_in[10];
  const float* b1 = (const float*)d_in[11];
  const float* gamma = (const float*)d_in[12];
  const float* beta = (const float*)d_in[13];
  const float* mu = (const float*)d_in[14];
  const float* var = (const float*)d_in[15];
  const float* W2 = (const float*)d_in[16];
  const float* b2 = (const float*)d_in[17];

  char* ws = (char*)d_ws;
  float* dstate = (float*)ws;                   // 4 MB
  u16* y = (u16*)(ws + ((size_t)4 << 20));      // 4 MB
  u16* qb = (u16*)(ws + ((size_t)8 << 20));     // 2 MB
  u16* kb = (u16*)(ws + ((size_t)10 << 20));    // 2 MB
  u16* vb = (u16*)(ws + ((size_t)12 << 20));    // 2 MB
  u16* attb = (u16*)(ws + ((size_t)14 << 20));  // 2 MB
  u16* wbf = (u16*)(ws + ((size_t)16 << 20));   // 23.6 MB
  float* scb = (float*)(ws + ((size_t)40 << 20));
  float* shb = (float*)(ws + ((size_t)41 << 20));

  k_setup<<<11556, 256, 0, stream>>>(Wq, Wk, Wv, Wm, W1, W2, gamma, beta, mu, var, b1,
                                     wbf, scb, shb);
  k_init<<<dim3(16, 4, 4), 256, 0, stream>>>(desc0, desc1, dstate, y);
  k_qkv0<<<256, 512, 0, stream>>>(y, wbf, bq, bk, bv, qb, kb, vb);

  for (int i = 0; i < 18; ++i) {
    int cross = i & 1;
    const u16* wl = wbf + (size_t)i * 655360;
    int nl = (i < 17) ? i + 1 : 0;
    const u16* wln = wbf + (size_t)nl * 655360;
    k_attn<<<dim3(16, 16), 512, 0, stream>>>(qb, kb, vb, attb, cross ? 2 : 0);
    k_post<<<256, 1024, 0, stream>>>(attb, wl, wln, bm + i * 256, scb + (size_t)i * 512,
                                     shb + (size_t)i * 512, b2 + i * 256, bq + nl * 256,
                                     bk + nl * 256, bv + nl * 256, dstate, y, qb, kb, vb,
                                     (float*)d_out, cross, i >> 1, i == 17);
  }
}